// Round 2
// baseline (305.710 us; speedup 1.0000x reference)
//
#include <hip/hip_runtime.h>
#include <math.h>

#define EMBED 1024
#define NHEAD 16
#define HDIM  64
#define BATCH 4
#define SEQ   2048
#define MROWS (BATCH * SEQ)   // 8192

typedef __attribute__((ext_vector_type(4))) short short4v;
typedef __attribute__((ext_vector_type(8))) short short8;
typedef __attribute__((ext_vector_type(4))) float floatx4;
typedef __attribute__((ext_vector_type(16))) float floatx16;

#if __has_builtin(__builtin_amdgcn_exp2f)
#define EXP2(x) __builtin_amdgcn_exp2f(x)
#else
#define EXP2(x) exp2f(x)
#endif

// RNE float -> bf16 (finite inputs only).
__device__ __forceinline__ unsigned short f2bf(float f) {
  unsigned u = __float_as_uint(f);
  u += 0x7fffu + ((u >> 16) & 1u);
  return (unsigned short)(u >> 16);
}

// Pack two floats as a bf16 pair. gfx950 has v_cvt_pk_bf16_f32 (1 VALU op).
#if __has_builtin(__builtin_amdgcn_cvt_pk_bf16_f32)
__device__ __forceinline__ unsigned pack2bf(float lo, float hi) {
  typedef __attribute__((ext_vector_type(2))) __bf16 bf2;
  union { bf2 b; unsigned u; } c;
  c.b = __builtin_amdgcn_cvt_pk_bf16_f32(lo, hi);
  return c.u;
}
#else
__device__ __forceinline__ unsigned pack2bf(float lo, float hi) {
  return ((__float_as_uint(lo) + 0x8000u) >> 16) |
         ((__float_as_uint(hi) + 0x8000u) & 0xffff0000u);
}
#endif

// Async global->LDS, 16 B per lane. lds dest MUST be wave-uniform base;
// HW adds lane*16.
__device__ __forceinline__ void gl_lds16(const void* g, void* l) {
  __builtin_amdgcn_global_load_lds(
      (const __attribute__((address_space(1))) unsigned int*)g,
      (__attribute__((address_space(3))) unsigned int*)l, 16, 0, 0);
}

// ---------------------------------------------------------------------------
// Cast fp32 -> bf16: x (8M elems) + 4 weights (1M each, contiguous dst).
// ---------------------------------------------------------------------------
__global__ __launch_bounds__(256) void cast_bf16_kernel(
    const float* __restrict__ x,  const float* __restrict__ wq,
    const float* __restrict__ wk, const float* __restrict__ wv,
    const float* __restrict__ wo,
    unsigned short* __restrict__ xb, unsigned short* __restrict__ wb) {
  const size_t NX = (size_t)MROWS * EMBED;                 // 2^23
  size_t i4 = ((size_t)blockIdx.x * 256 + threadIdx.x) * 4;
  const float* src;
  unsigned short* dst;
  size_t off;
  if (i4 < NX) {
    src = x; dst = xb; off = i4;
  } else {
    size_t j = i4 - NX;
    int r = (int)(j >> 20);
    off = j & ((1u << 20) - 1);
    src = (r == 0) ? wq : (r == 1) ? wk : (r == 2) ? wv : wo;
    dst = wb + ((size_t)r << 20);
  }
  float4 v = *(const float4*)(src + off);
  ushort4 o;
  o.x = f2bf(v.x); o.y = f2bf(v.y); o.z = f2bf(v.z); o.w = f2bf(v.w);
  *(ushort4*)(dst + off) = o;
}

// ---------------------------------------------------------------------------
// Shared 128x128xK bf16 GEMM core (m97 structure): Y = A @ B^T fragments.
// ---------------------------------------------------------------------------
__device__ __forceinline__ void gemm_core(
    const unsigned short* __restrict__ Amat,
    const unsigned short* __restrict__ Bmat,
    int mBase, int nBase,
    unsigned short* As, unsigned short* Bs,
    floatx4 acc[4][4]) {
  const int t = threadIdx.x;
  const int lane = t & 63, w = t >> 6;
  const int wr = w >> 1, wc = w & 1;
  const int quad = lane >> 4, l15 = lane & 15;

  const int f0 = (w * 2 + 0) * 64 + lane;
  const int f1 = (w * 2 + 1) * 64 + lane;
  const unsigned short* ga0 = Amat + (size_t)(mBase + (f0 >> 2)) * EMBED + (f0 & 3) * 8;
  const unsigned short* ga1 = Amat + (size_t)(mBase + (f1 >> 2)) * EMBED + (f1 & 3) * 8;
  const unsigned short* gb0 = Bmat + (size_t)(nBase + (f0 >> 2)) * EMBED + (f0 & 3) * 8;
  const unsigned short* gb1 = Bmat + (size_t)(nBase + (f1 >> 2)) * EMBED + (f1 & 3) * 8;
  unsigned short* la0 = As + (w * 2 + 0) * 512;
  unsigned short* la1 = As + (w * 2 + 1) * 512;
  unsigned short* lb0 = Bs + (w * 2 + 0) * 512;
  unsigned short* lb1 = Bs + (w * 2 + 1) * 512;

  for (int kb = 0; kb < EMBED; kb += 32) {
    __syncthreads();
    gl_lds16(ga0 + kb, la0);
    gl_lds16(ga1 + kb, la1);
    gl_lds16(gb0 + kb, lb0);
    gl_lds16(gb1 + kb, lb1);
    __syncthreads();
    short8 a[4], b[4];
#pragma unroll
    for (int mi = 0; mi < 4; ++mi)
      a[mi] = *(const short8*)&As[(wr * 64 + mi * 16 + l15) * 32 + quad * 8];
#pragma unroll
    for (int ni = 0; ni < 4; ++ni)
      b[ni] = *(const short8*)&Bs[(wc * 64 + ni * 16 + l15) * 32 + quad * 8];
#pragma unroll
    for (int mi = 0; mi < 4; ++mi)
#pragma unroll
      for (int ni = 0; ni < 4; ++ni)
        acc[mi][ni] = __builtin_amdgcn_mfma_f32_16x16x32_bf16(
            a[mi], b[ni], acc[mi][ni], 0, 0, 0);
  }
}

// ---------------------------------------------------------------------------
// QKV projection. Q is pre-scaled by C=(1/8)*log2(e) so attention's exp2
// argument is the raw QK^T score. Q,K: bf16 [b,h,s,d]; V: [b,h,d,s].
// ---------------------------------------------------------------------------
__global__ __launch_bounds__(256) void proj_qkv_bf16(
    const unsigned short* __restrict__ xb,
    const unsigned short* __restrict__ wb,
    unsigned short* __restrict__ qkv) {
  const int which = blockIdx.z;
  const unsigned short* W = wb + ((size_t)which << 20);
  const int nBase = blockIdx.x * 128;
  const int mBase = blockIdx.y * 128;

  __shared__ unsigned short As[128 * 32];
  __shared__ unsigned short Bs[128 * 32];

  floatx4 acc[4][4] = {};
  gemm_core(xb, W, mBase, nBase, As, Bs, acc);

  const int t = threadIdx.x;
  const int lane = t & 63, w = t >> 6;
  const int wr = w >> 1, wc = w & 1;
  const int quad = lane >> 4, l15 = lane & 15;

  unsigned short* out = qkv + (size_t)which * MROWS * EMBED;
  if (which < 2) {
    const float scale = (which == 0) ? 0.18033688f : 1.0f;  // (1/8)*log2(e)
#pragma unroll
    for (int mi = 0; mi < 4; ++mi)
#pragma unroll
      for (int ni = 0; ni < 4; ++ni) {
        const int n = nBase + wc * 64 + ni * 16 + l15;
        const int h = n >> 6, d = n & 63;
#pragma unroll
        for (int r = 0; r < 4; ++r) {
          const int m = mBase + wr * 64 + mi * 16 + quad * 4 + r;
          const int b = m >> 11, s = m & (SEQ - 1);
          out[(((size_t)(b * NHEAD + h) * SEQ) + s) * HDIM + d] =
              f2bf(acc[mi][ni][r] * scale);
        }
      }
  } else {
    // V^T: [b,h,d,s] — 4 consecutive s per lane -> packed 8 B store.
#pragma unroll
    for (int mi = 0; mi < 4; ++mi) {
      const int m0 = mBase + wr * 64 + mi * 16 + quad * 4;
      const int b = m0 >> 11, s0 = m0 & (SEQ - 1);
#pragma unroll
      for (int ni = 0; ni < 4; ++ni) {
        const int n = nBase + wc * 64 + ni * 16 + l15;
        const int h = n >> 6, d = n & 63;
        ushort4 pk;
        pk.x = f2bf(acc[mi][ni][0]); pk.y = f2bf(acc[mi][ni][1]);
        pk.z = f2bf(acc[mi][ni][2]); pk.w = f2bf(acc[mi][ni][3]);
        *(ushort4*)&out[((size_t)(b * NHEAD + h) * HDIM + d) * SEQ + s0] = pk;
      }
    }
  }
}

// ---------------------------------------------------------------------------
// MFMA flash attention, transposed-score formulation.
// R9 (= R8 + uniform LDS staging base): double-buffered K/V tiles (64 KB
// LDS), 512-thread blocks (8 waves, 256 queries), prefetch next tile with
// global_load_lds BEFORE computing the current one, raw s_barrier + counted
// s_waitcnt vmcnt(4) so the prefetch stays in flight across the barrier
// (never drain vmcnt to 0 in-loop), s_setprio(1) around MFMA clusters.
// Grid 512 = 2 blocks/CU; __launch_bounds__(512,4) pins VGPR<=128.
// ---------------------------------------------------------------------------
__global__ __launch_bounds__(512, 4) void attn_mfma(
    const unsigned short* __restrict__ qkv,
    unsigned short* __restrict__ aout) {
  const unsigned short* Q = qkv;
  const unsigned short* K = qkv + (size_t)MROWS * EMBED;
  const unsigned short* V = qkv + 2 * (size_t)MROWS * EMBED;

  // XCD-locality decode: all 8 q-blocks of one bh land on one XCD.
  const int id = blockIdx.x;
  const int xcd = id & 7, slot = id >> 3;      // slot 0..63
  const int bh = xcd * 8 + (slot >> 3);
  const int qBase = (slot & 7) * 256;

  __shared__ unsigned short Ks[2 * 128 * 64];  // [buf][key][d], XOR-8 swizzled
  __shared__ unsigned short Vs[2 * 64 * 128];  // [buf][d][key], XOR-16 swizzled

  const int t = threadIdx.x;
  const int lane = t & 63, w = t >> 6;         // w 0..7
  const int h2 = lane >> 5;     // lane half (k-group selector in A/B frags)
  const int q31 = lane & 31;    // query within wave / col within tile

  // Q B-frags (pre-scaled by (1/8)*log2e): B[k=d][n=q].
  const unsigned short* qrow =
      Q + ((size_t)bh * SEQ + qBase + w * 32 + q31) * HDIM;
  short8 qa[4];
#pragma unroll
  for (int ds = 0; ds < 4; ++ds)
    qa[ds] = *(const short8*)(qrow + ds * 16 + h2 * 8);

  // Staging: 512 threads stage 16 KB K + 16 KB V per tile -> 2 K-chunks +
  // 2 V-chunks of 16 B per thread (4 gl_lds per tile). Chunk index
  // c = i*512 + w*64 + lane occupies LDS bytes [c*16, c*16+16); the LDS
  // pointer passed to gl_lds16 is the wave-uniform part (HW adds lane*16),
  // the global pointer carries the per-lane swizzled address.
  const unsigned short* kbase = K + (size_t)bh * SEQ * HDIM;
  const unsigned short* vbase = V + (size_t)bh * HDIM * SEQ;
  const unsigned short* gk[2];
  const unsigned short* gv[2];
  unsigned short* lk[2];
  unsigned short* lv[2];
#pragma unroll
  for (int i = 0; i < 2; ++i) {
    const int c = i * 512 + t;                 // per-lane chunk 0..1023
    const int krow = c >> 3, kgrp = (c & 7) ^ (krow & 7);
    gk[i] = kbase + (size_t)krow * HDIM + kgrp * 8;
    const int vd = c >> 4, vj = (c & 15) ^ (vd & 15);
    gv[i] = vbase + (size_t)vd * SEQ + vj * 8;
    const int cu = i * 512 + w * 64;           // wave-uniform chunk base
    lk[i] = Ks + cu * 8;
    lv[i] = Vs + cu * 8;
  }

  floatx16 ot0 = {}, ot1 = {};    // O^T accum: d-groups 0-31, 32-63
  float lacc = 0.0f;              // per-lane partial softmax denominator

  // Prologue: stage tile 0 into buffer 0.
#pragma unroll
  for (int i = 0; i < 2; ++i) {
    gl_lds16(gk[i], lk[i]);
    gl_lds16(gv[i], lv[i]);
  }

  for (int kt = 0; kt < SEQ; kt += 128) {
    const int cb = (kt >> 7) & 1;              // current buffer
    const int nb = cb ^ 1;                     // prefetch buffer
    const int nxt = (kt + 128) & (SEQ - 1);    // last iter re-stages tile 0
                                               // (keeps vmcnt count uniform)
    const int sOff = nb * 8192;                // ushort offset of prefetch buf
#pragma unroll
    for (int i = 0; i < 2; ++i) {
      gl_lds16(gk[i] + (size_t)nxt * HDIM, lk[i] + sOff);
      gl_lds16(gv[i] + nxt, lv[i] + sOff);
    }
    __builtin_amdgcn_sched_barrier(0);
    // Wait only for the PREVIOUS tile's 4 loads; this tile's 4 stay in
    // flight across the barrier (T4: never drain vmcnt to 0 in the loop).
    asm volatile("s_waitcnt vmcnt(4)" ::: "memory");
    __builtin_amdgcn_s_barrier();

    const int kOff = cb * 8192;                // ushort offsets, current buf
    const int vOff = cb * 8192;

#pragma unroll
    for (int sub = 0; sub < 2; ++sub) {
      const int koff = sub * 64;

      // S^T = K·Q^T: A[m=key][k=d] from Ks (swizzled b128), B = qa regs.
      floatx16 st0 = {}, st1 = {};
      __builtin_amdgcn_s_setprio(1);
#pragma unroll
      for (int ds = 0; ds < 4; ++ds) {
        const int g = ds * 2 + h2;
        const int k0 = koff + q31;
        short8 ka0 = *(const short8*)&Ks[kOff + k0 * 64 + ((g ^ (q31 & 7)) * 8)];
        st0 = __builtin_amdgcn_mfma_f32_32x32x16_bf16(ka0, qa[ds], st0, 0, 0, 0);
        const int k1 = koff + 32 + q31;
        short8 ka1 = *(const short8*)&Ks[kOff + k1 * 64 + ((g ^ (q31 & 7)) * 8)];
        st1 = __builtin_amdgcn_mfma_f32_32x32x16_bf16(ka1, qa[ds], st1, 0, 0, 0);
      }
      __builtin_amdgcn_s_setprio(0);

      // P^T = exp2(S^T), fused exp+pack (short live ranges). All of a
      // lane's regs belong to its own query (col=q31) -> plain fp32 sum.
      unsigned pk0[8], pk1[8];
#pragma unroll
      for (int i = 0; i < 8; ++i) {
        float a0 = EXP2(st0[2 * i]), b0 = EXP2(st0[2 * i + 1]);
        float a1 = EXP2(st1[2 * i]), b1 = EXP2(st1[2 * i + 1]);
        lacc += (a0 + b0) + (a1 + b1);
        pk0[i] = pack2bf(a0, b0);
        pk1[i] = pack2bf(a1, b1);
      }

      // PV: O^T += V^T·P^T, 8 k-steps of 8 keys (32x32x8 MFMA).
      __builtin_amdgcn_s_setprio(1);
#pragma unroll
      for (int s = 0; s < 8; ++s) {
        const unsigned* pk = (s < 4) ? pk0 : pk1;
        const int rg = s & 3;
        union { unsigned u[2]; short4v v; } pb;
        pb.u[0] = pk[2 * rg + 0];
        pb.u[1] = pk[2 * rg + 1];

        const int g = sub * 8 + s;
        const int pos = ((g ^ (q31 & 15)) * 8) + h2 * 4;
        short4v va0 = *(const short4v*)&Vs[vOff + q31 * 128 + pos];
        ot0 = __builtin_amdgcn_mfma_f32_32x32x8bf16_1k(va0, pb.v, ot0, 0, 0, 0);
        short4v va1 = *(const short4v*)&Vs[vOff + (32 + q31) * 128 + pos];
        ot1 = __builtin_amdgcn_mfma_f32_32x32x8bf16_1k(va1, pb.v, ot1, 0, 0, 0);
      }
      __builtin_amdgcn_s_setprio(0);
    }

    __builtin_amdgcn_sched_barrier(0);
    __builtin_amdgcn_s_barrier();   // all waves done reading buf[cb]; next
                                    // iter's prefetch may overwrite it
  }
  asm volatile("s_waitcnt vmcnt(0)" ::: "memory");  // drain stray prefetch

  // Combine the two lane-halves' partial sums for this query.
  const float tot = lacc + __shfl_xor(lacc, 32);
  const float inv = 1.0f / tot;

  // O^T C-layout: col=q (lane), row=d=(reg&3)+8*(reg>>2)+4*h2 (+32 for ot1).
  const int b = bh >> 4, hh = bh & 15;
  unsigned short* orow =
      aout + ((size_t)b * SEQ + qBase + w * 32 + q31) * EMBED + hh * HDIM;
#pragma unroll
  for (int rg = 0; rg < 4; ++rg) {
    const int d0 = rg * 8 + h2 * 4;
    ushort4 p0, p1;
    p0.x = f2bf(ot0[4 * rg + 0] * inv); p0.y = f2bf(ot0[4 * rg + 1] * inv);
    p0.z = f2bf(ot0[4 * rg + 2] * inv); p0.w = f2bf(ot0[4 * rg + 3] * inv);
    *(ushort4*)(orow + d0) = p0;
    p1.x = f2bf(ot1[4 * rg + 0] * inv); p1.y = f2bf(ot1[4 * rg + 1] * inv);
    p1.z = f2bf(ot1[4 * rg + 2] * inv); p1.w = f2bf(ot1[4 * rg + 3] * inv);
    *(ushort4*)(orow + 32 + d0) = p1;
  }
}

// ---------------------------------------------------------------------------
// Output projection: fp32 result straight from accumulators.
// ---------------------------------------------------------------------------
__global__ __launch_bounds__(256) void out_proj_bf16(
    const unsigned short* __restrict__ aout,
    const unsigned short* __restrict__ wb,
    float* __restrict__ Cout) {
  const int nBase = blockIdx.x * 128;
  const int mBase = blockIdx.y * 128;

  __shared__ unsigned short As[128 * 32];
  __shared__ unsigned short Bs[128 * 32];

  floatx4 acc[4][4] = {};
  gemm_core(aout, wb + ((size_t)3 << 20), mBase, nBase, As, Bs, acc);

  const int t = threadIdx.x;
  const int lane = t & 63, w = t >> 6;
  const int wr = w >> 1, wc = w & 1;
  const int quad = lane >> 4, l15 = lane & 15;

#pragma unroll
  for (int mi = 0; mi < 4; ++mi)
#pragma unroll
    for (int ni = 0; ni < 4; ++ni) {
      const int n = nBase + wc * 64 + ni * 16 + l15;
#pragma unroll
      for (int r = 0; r < 4; ++r) {
        const int m = mBase + wr * 64 + mi * 16 + quad * 4 + r;
        Cout[(size_t)m * EMBED + n] = acc[mi][ni][r];
      }
    }
}

extern "C" void kernel_launch(void* const* d_in, const int* in_sizes, int n_in,
                              void* d_out, int out_size, void* d_ws, size_t ws_size,
                              hipStream_t stream) {
  const float* x  = (const float*)d_in[0];
  const float* wq = (const float*)d_in[1];
  const float* wk = (const float*)d_in[2];
  const float* wv = (const float*)d_in[3];
  const float* wo = (const float*)d_in[4];
  float* out = (float*)d_out;

  char* ws = (char*)d_ws;
  unsigned short* xb   = (unsigned short*)(ws);                  // 16.8 MB
  unsigned short* wb   = (unsigned short*)(ws + (16u << 20));    // 8.4 MB
  unsigned short* qkv  = (unsigned short*)(ws + (26u << 20));    // 50.3 MB
  unsigned short* aout = (unsigned short*)(ws + (76u << 20));    // 16.8 MB

  cast_bf16_kernel<<<12288, 256, 0, stream>>>(x, wq, wk, wv, wo, xb, wb);
  proj_qkv_bf16<<<dim3(EMBED / 128, MROWS / 128, 3), 256, 0, stream>>>(xb, wb, qkv);
  attn_mfma<<<512, 512, 0, stream>>>(qkv, aout);
  out_proj_bf16<<<dim3(EMBED / 128, MROWS / 128), 256, 0, stream>>>(aout, wb, out);
}

// Round 3
// 286.420 us; speedup vs baseline: 1.0673x; 1.0673x over previous
//
#include <hip/hip_runtime.h>
#include <math.h>

#define EMBED 1024
#define NHEAD 16
#define HDIM  64
#define BATCH 4
#define SEQ   2048
#define MROWS (BATCH * SEQ)   // 8192

typedef __attribute__((ext_vector_type(4))) short short4v;
typedef __attribute__((ext_vector_type(8))) short short8;
typedef __attribute__((ext_vector_type(4))) float floatx4;
typedef __attribute__((ext_vector_type(16))) float floatx16;

#if __has_builtin(__builtin_amdgcn_exp2f)
#define EXP2(x) __builtin_amdgcn_exp2f(x)
#else
#define EXP2(x) exp2f(x)
#endif

// RNE float -> bf16 (finite inputs only).
__device__ __forceinline__ unsigned short f2bf(float f) {
  unsigned u = __float_as_uint(f);
  u += 0x7fffu + ((u >> 16) & 1u);
  return (unsigned short)(u >> 16);
}

// Pack two floats as a bf16 pair. gfx950 has v_cvt_pk_bf16_f32 (1 VALU op).
#if __has_builtin(__builtin_amdgcn_cvt_pk_bf16_f32)
__device__ __forceinline__ unsigned pack2bf(float lo, float hi) {
  typedef __attribute__((ext_vector_type(2))) __bf16 bf2;
  union { bf2 b; unsigned u; } c;
  c.b = __builtin_amdgcn_cvt_pk_bf16_f32(lo, hi);
  return c.u;
}
#else
__device__ __forceinline__ unsigned pack2bf(float lo, float hi) {
  return ((__float_as_uint(lo) + 0x8000u) >> 16) |
         ((__float_as_uint(hi) + 0x8000u) & 0xffff0000u);
}
#endif

// Async global->LDS, 16 B per lane. lds dest MUST be wave-uniform base;
// HW adds lane*16.
__device__ __forceinline__ void gl_lds16(const void* g, void* l) {
  __builtin_amdgcn_global_load_lds(
      (const __attribute__((address_space(1))) unsigned int*)g,
      (__attribute__((address_space(3))) unsigned int*)l, 16, 0, 0);
}

// ---------------------------------------------------------------------------
// Cast fp32 -> bf16: x (8M elems) + 4 weights (1M each, contiguous dst).
// ---------------------------------------------------------------------------
__global__ __launch_bounds__(256) void cast_bf16_kernel(
    const float* __restrict__ x,  const float* __restrict__ wq,
    const float* __restrict__ wk, const float* __restrict__ wv,
    const float* __restrict__ wo,
    unsigned short* __restrict__ xb, unsigned short* __restrict__ wb) {
  const size_t NX = (size_t)MROWS * EMBED;                 // 2^23
  size_t i4 = ((size_t)blockIdx.x * 256 + threadIdx.x) * 4;
  const float* src;
  unsigned short* dst;
  size_t off;
  if (i4 < NX) {
    src = x; dst = xb; off = i4;
  } else {
    size_t j = i4 - NX;
    int r = (int)(j >> 20);
    off = j & ((1u << 20) - 1);
    src = (r == 0) ? wq : (r == 1) ? wk : (r == 2) ? wv : wo;
    dst = wb + ((size_t)r << 20);
  }
  float4 v = *(const float4*)(src + off);
  ushort4 o;
  o.x = f2bf(v.x); o.y = f2bf(v.y); o.z = f2bf(v.z); o.w = f2bf(v.w);
  *(ushort4*)(dst + off) = o;
}

// ---------------------------------------------------------------------------
// Shared 128x128xK bf16 GEMM core (m97 structure): Y = A @ B^T fragments.
// ---------------------------------------------------------------------------
__device__ __forceinline__ void gemm_core(
    const unsigned short* __restrict__ Amat,
    const unsigned short* __restrict__ Bmat,
    int mBase, int nBase,
    unsigned short* As, unsigned short* Bs,
    floatx4 acc[4][4]) {
  const int t = threadIdx.x;
  const int lane = t & 63, w = t >> 6;
  const int wr = w >> 1, wc = w & 1;
  const int quad = lane >> 4, l15 = lane & 15;

  const int f0 = (w * 2 + 0) * 64 + lane;
  const int f1 = (w * 2 + 1) * 64 + lane;
  const unsigned short* ga0 = Amat + (size_t)(mBase + (f0 >> 2)) * EMBED + (f0 & 3) * 8;
  const unsigned short* ga1 = Amat + (size_t)(mBase + (f1 >> 2)) * EMBED + (f1 & 3) * 8;
  const unsigned short* gb0 = Bmat + (size_t)(nBase + (f0 >> 2)) * EMBED + (f0 & 3) * 8;
  const unsigned short* gb1 = Bmat + (size_t)(nBase + (f1 >> 2)) * EMBED + (f1 & 3) * 8;
  unsigned short* la0 = As + (w * 2 + 0) * 512;
  unsigned short* la1 = As + (w * 2 + 1) * 512;
  unsigned short* lb0 = Bs + (w * 2 + 0) * 512;
  unsigned short* lb1 = Bs + (w * 2 + 1) * 512;

  for (int kb = 0; kb < EMBED; kb += 32) {
    __syncthreads();
    gl_lds16(ga0 + kb, la0);
    gl_lds16(ga1 + kb, la1);
    gl_lds16(gb0 + kb, lb0);
    gl_lds16(gb1 + kb, lb1);
    __syncthreads();
    short8 a[4], b[4];
#pragma unroll
    for (int mi = 0; mi < 4; ++mi)
      a[mi] = *(const short8*)&As[(wr * 64 + mi * 16 + l15) * 32 + quad * 8];
#pragma unroll
    for (int ni = 0; ni < 4; ++ni)
      b[ni] = *(const short8*)&Bs[(wc * 64 + ni * 16 + l15) * 32 + quad * 8];
#pragma unroll
    for (int mi = 0; mi < 4; ++mi)
#pragma unroll
      for (int ni = 0; ni < 4; ++ni)
        acc[mi][ni] = __builtin_amdgcn_mfma_f32_16x16x32_bf16(
            a[mi], b[ni], acc[mi][ni], 0, 0, 0);
  }
}

// ---------------------------------------------------------------------------
// QKV projection. Q is pre-scaled by C=(1/8)*log2(e) so attention's exp2
// argument is the raw QK^T score. Q,K: bf16 [b,h,s,d]; V: [b,h,d,s].
// ---------------------------------------------------------------------------
__global__ __launch_bounds__(256) void proj_qkv_bf16(
    const unsigned short* __restrict__ xb,
    const unsigned short* __restrict__ wb,
    unsigned short* __restrict__ qkv) {
  const int which = blockIdx.z;
  const unsigned short* W = wb + ((size_t)which << 20);
  const int nBase = blockIdx.x * 128;
  const int mBase = blockIdx.y * 128;

  __shared__ unsigned short As[128 * 32];
  __shared__ unsigned short Bs[128 * 32];

  floatx4 acc[4][4] = {};
  gemm_core(xb, W, mBase, nBase, As, Bs, acc);

  const int t = threadIdx.x;
  const int lane = t & 63, w = t >> 6;
  const int wr = w >> 1, wc = w & 1;
  const int quad = lane >> 4, l15 = lane & 15;

  unsigned short* out = qkv + (size_t)which * MROWS * EMBED;
  if (which < 2) {
    const float scale = (which == 0) ? 0.18033688f : 1.0f;  // (1/8)*log2(e)
#pragma unroll
    for (int mi = 0; mi < 4; ++mi)
#pragma unroll
      for (int ni = 0; ni < 4; ++ni) {
        const int n = nBase + wc * 64 + ni * 16 + l15;
        const int h = n >> 6, d = n & 63;
#pragma unroll
        for (int r = 0; r < 4; ++r) {
          const int m = mBase + wr * 64 + mi * 16 + quad * 4 + r;
          const int b = m >> 11, s = m & (SEQ - 1);
          out[(((size_t)(b * NHEAD + h) * SEQ) + s) * HDIM + d] =
              f2bf(acc[mi][ni][r] * scale);
        }
      }
  } else {
    // V^T: [b,h,d,s] — 4 consecutive s per lane -> packed 8 B store.
#pragma unroll
    for (int mi = 0; mi < 4; ++mi) {
      const int m0 = mBase + wr * 64 + mi * 16 + quad * 4;
      const int b = m0 >> 11, s0 = m0 & (SEQ - 1);
#pragma unroll
      for (int ni = 0; ni < 4; ++ni) {
        const int n = nBase + wc * 64 + ni * 16 + l15;
        const int h = n >> 6, d = n & 63;
        ushort4 pk;
        pk.x = f2bf(acc[mi][ni][0]); pk.y = f2bf(acc[mi][ni][1]);
        pk.z = f2bf(acc[mi][ni][2]); pk.w = f2bf(acc[mi][ni][3]);
        *(ushort4*)&out[((size_t)(b * NHEAD + h) * HDIM + d) * SEQ + s0] = pk;
      }
    }
  }
}

// ---------------------------------------------------------------------------
// MFMA flash attention, transposed-score formulation.
// R10: q-doubling. Each wave owns 64 queries as two 32-query MFMA column
// groups (A: +0, B: +32). Every K-fragment (ka) and V-fragment (va) LDS
// read now feeds TWO MFMAs (one per group), halving LDS bytes and issue
// slots per FLOP — the R9 profile showed no pipe >50% with per-wave LDS
// amplification (each wave re-reads the whole 32KB K/V tile) as the
// structural cost. Block = 8 waves x 64 q = 512 queries; grid 256 =
// 1 block/CU; LDS 64KB dbuf + counted vmcnt(4) + setprio kept from R9.
// __launch_bounds__(512,2): 2 waves/SIMD, VGPR cap 256 (est ~150V+64A).
// ---------------------------------------------------------------------------
__global__ __launch_bounds__(512, 2) void attn_mfma(
    const unsigned short* __restrict__ qkv,
    unsigned short* __restrict__ aout) {
  const unsigned short* Q = qkv;
  const unsigned short* K = qkv + (size_t)MROWS * EMBED;
  const unsigned short* V = qkv + 2 * (size_t)MROWS * EMBED;

  // XCD-locality decode: all 4 q-blocks of one bh land on one XCD.
  const int id = blockIdx.x;
  const int xcd = id & 7, slot = id >> 3;      // slot 0..31
  const int bh = xcd * 8 + (slot >> 2);
  const int qBase = (slot & 3) * 512;

  __shared__ unsigned short Ks[2 * 128 * 64];  // [buf][key][d], XOR-8 swizzled
  __shared__ unsigned short Vs[2 * 64 * 128];  // [buf][d][key], XOR-16 swizzled

  const int t = threadIdx.x;
  const int lane = t & 63, w = t >> 6;         // w 0..7
  const int h2 = lane >> 5;     // lane half (k-group selector in A/B frags)
  const int q31 = lane & 31;    // query within group / col within MFMA tile

  // Q B-frags (pre-scaled by (1/8)*log2e): B[k=d][n=q]. Two query groups.
  const unsigned short* qrowA =
      Q + ((size_t)bh * SEQ + qBase + w * 64 + q31) * HDIM;
  const unsigned short* qrowB = qrowA + 32 * HDIM;
  short8 qaA[4], qaB[4];
#pragma unroll
  for (int ds = 0; ds < 4; ++ds) {
    qaA[ds] = *(const short8*)(qrowA + ds * 16 + h2 * 8);
    qaB[ds] = *(const short8*)(qrowB + ds * 16 + h2 * 8);
  }

  // Staging: 512 threads stage 16 KB K + 16 KB V per tile -> 2 K-chunks +
  // 2 V-chunks of 16 B per thread (4 gl_lds per tile). Chunk index
  // c = i*512 + w*64 + lane occupies LDS bytes [c*16, c*16+16); the LDS
  // pointer passed to gl_lds16 is the wave-uniform part (HW adds lane*16),
  // the global pointer carries the per-lane swizzled address.
  const unsigned short* kbase = K + (size_t)bh * SEQ * HDIM;
  const unsigned short* vbase = V + (size_t)bh * HDIM * SEQ;
  const unsigned short* gk[2];
  const unsigned short* gv[2];
  unsigned short* lk[2];
  unsigned short* lv[2];
#pragma unroll
  for (int i = 0; i < 2; ++i) {
    const int c = i * 512 + t;                 // per-lane chunk 0..1023
    const int krow = c >> 3, kgrp = (c & 7) ^ (krow & 7);
    gk[i] = kbase + (size_t)krow * HDIM + kgrp * 8;
    const int vd = c >> 4, vj = (c & 15) ^ (vd & 15);
    gv[i] = vbase + (size_t)vd * SEQ + vj * 8;
    const int cu = i * 512 + w * 64;           // wave-uniform chunk base
    lk[i] = Ks + cu * 8;
    lv[i] = Vs + cu * 8;
  }

  floatx16 otA0 = {}, otA1 = {};  // group A O^T accum: d 0-31, 32-63
  floatx16 otB0 = {}, otB1 = {};  // group B
  float laccA = 0.0f, laccB = 0.0f;

  // Prologue: stage tile 0 into buffer 0.
#pragma unroll
  for (int i = 0; i < 2; ++i) {
    gl_lds16(gk[i], lk[i]);
    gl_lds16(gv[i], lv[i]);
  }

  for (int kt = 0; kt < SEQ; kt += 128) {
    const int cb = (kt >> 7) & 1;              // current buffer
    const int nb = cb ^ 1;                     // prefetch buffer
    const int nxt = (kt + 128) & (SEQ - 1);    // last iter re-stages tile 0
                                               // (keeps vmcnt count uniform)
    const int sOff = nb * 8192;                // ushort offset of prefetch buf
#pragma unroll
    for (int i = 0; i < 2; ++i) {
      gl_lds16(gk[i] + (size_t)nxt * HDIM, lk[i] + sOff);
      gl_lds16(gv[i] + nxt, lv[i] + sOff);
    }
    __builtin_amdgcn_sched_barrier(0);
    // Wait only for the PREVIOUS tile's 4 loads; this tile's 4 stay in
    // flight across the barrier (T4: never drain vmcnt to 0 in the loop).
    asm volatile("s_waitcnt vmcnt(4)" ::: "memory");
    __builtin_amdgcn_s_barrier();

    const int kOff = cb * 8192;                // ushort offsets, current buf
    const int vOff = cb * 8192;

#pragma unroll
    for (int sub = 0; sub < 2; ++sub) {
      const int koff = sub * 64;

      // S^T = K·Q^T: A[m=key][k=d] from Ks (swizzled b128), B = qa regs.
      // Each ka read feeds BOTH query groups (2 MFMAs per read).
      floatx16 stA0 = {}, stA1 = {}, stB0 = {}, stB1 = {};
      __builtin_amdgcn_s_setprio(1);
#pragma unroll
      for (int ds = 0; ds < 4; ++ds) {
        const int g = ds * 2 + h2;
        const int k0 = koff + q31;
        short8 ka0 = *(const short8*)&Ks[kOff + k0 * 64 + ((g ^ (q31 & 7)) * 8)];
        stA0 = __builtin_amdgcn_mfma_f32_32x32x16_bf16(ka0, qaA[ds], stA0, 0, 0, 0);
        stB0 = __builtin_amdgcn_mfma_f32_32x32x16_bf16(ka0, qaB[ds], stB0, 0, 0, 0);
        const int k1 = koff + 32 + q31;
        short8 ka1 = *(const short8*)&Ks[kOff + k1 * 64 + ((g ^ (q31 & 7)) * 8)];
        stA1 = __builtin_amdgcn_mfma_f32_32x32x16_bf16(ka1, qaA[ds], stA1, 0, 0, 0);
        stB1 = __builtin_amdgcn_mfma_f32_32x32x16_bf16(ka1, qaB[ds], stB1, 0, 0, 0);
      }
      __builtin_amdgcn_s_setprio(0);

      // P^T = exp2(S^T), fused exp+pack (short live ranges). All of a
      // lane's regs belong to its own query (col=q31) -> plain fp32 sum.
      unsigned pkA0[8], pkA1[8], pkB0[8], pkB1[8];
#pragma unroll
      for (int i = 0; i < 8; ++i) {
        float a0 = EXP2(stA0[2 * i]), b0 = EXP2(stA0[2 * i + 1]);
        float a1 = EXP2(stA1[2 * i]), b1 = EXP2(stA1[2 * i + 1]);
        laccA += (a0 + b0) + (a1 + b1);
        pkA0[i] = pack2bf(a0, b0);
        pkA1[i] = pack2bf(a1, b1);
        float c0 = EXP2(stB0[2 * i]), d0 = EXP2(stB0[2 * i + 1]);
        float c1 = EXP2(stB1[2 * i]), d1 = EXP2(stB1[2 * i + 1]);
        laccB += (c0 + d0) + (c1 + d1);
        pkB0[i] = pack2bf(c0, d0);
        pkB1[i] = pack2bf(c1, d1);
      }

      // PV: O^T += V^T·P^T, 8 k-steps of 8 keys (32x32x8 MFMA). Each va
      // read feeds BOTH query groups (2 MFMAs per read).
      __builtin_amdgcn_s_setprio(1);
#pragma unroll
      for (int s = 0; s < 8; ++s) {
        const unsigned* pkA = (s < 4) ? pkA0 : pkA1;
        const unsigned* pkB = (s < 4) ? pkB0 : pkB1;
        const int rg = s & 3;
        union { unsigned u[2]; short4v v; } pbA, pbB;
        pbA.u[0] = pkA[2 * rg + 0];
        pbA.u[1] = pkA[2 * rg + 1];
        pbB.u[0] = pkB[2 * rg + 0];
        pbB.u[1] = pkB[2 * rg + 1];

        const int g = sub * 8 + s;
        const int pos = ((g ^ (q31 & 15)) * 8) + h2 * 4;
        short4v va0 = *(const short4v*)&Vs[vOff + q31 * 128 + pos];
        otA0 = __builtin_amdgcn_mfma_f32_32x32x8bf16_1k(va0, pbA.v, otA0, 0, 0, 0);
        otB0 = __builtin_amdgcn_mfma_f32_32x32x8bf16_1k(va0, pbB.v, otB0, 0, 0, 0);
        short4v va1 = *(const short4v*)&Vs[vOff + (32 + q31) * 128 + pos];
        otA1 = __builtin_amdgcn_mfma_f32_32x32x8bf16_1k(va1, pbA.v, otA1, 0, 0, 0);
        otB1 = __builtin_amdgcn_mfma_f32_32x32x8bf16_1k(va1, pbB.v, otB1, 0, 0, 0);
      }
      __builtin_amdgcn_s_setprio(0);
    }

    __builtin_amdgcn_sched_barrier(0);
    __builtin_amdgcn_s_barrier();   // all waves done reading buf[cb]; next
                                    // iter's prefetch may overwrite it
  }
  asm volatile("s_waitcnt vmcnt(0)" ::: "memory");  // drain stray prefetch

  // Combine the two lane-halves' partial sums for each query group.
  const float totA = laccA + __shfl_xor(laccA, 32);
  const float totB = laccB + __shfl_xor(laccB, 32);
  const float invA = 1.0f / totA;
  const float invB = 1.0f / totB;

  // O^T C-layout: col=q (lane), row=d=(reg&3)+8*(reg>>2)+4*h2 (+32 for *1).
  const int b = bh >> 4, hh = bh & 15;
  unsigned short* orowA =
      aout + ((size_t)b * SEQ + qBase + w * 64 + q31) * EMBED + hh * HDIM;
  unsigned short* orowB = orowA + (size_t)32 * EMBED;
#pragma unroll
  for (int rg = 0; rg < 4; ++rg) {
    const int d0 = rg * 8 + h2 * 4;
    ushort4 p0, p1;
    p0.x = f2bf(otA0[4 * rg + 0] * invA); p0.y = f2bf(otA0[4 * rg + 1] * invA);
    p0.z = f2bf(otA0[4 * rg + 2] * invA); p0.w = f2bf(otA0[4 * rg + 3] * invA);
    *(ushort4*)(orowA + d0) = p0;
    p1.x = f2bf(otA1[4 * rg + 0] * invA); p1.y = f2bf(otA1[4 * rg + 1] * invA);
    p1.z = f2bf(otA1[4 * rg + 2] * invA); p1.w = f2bf(otA1[4 * rg + 3] * invA);
    *(ushort4*)(orowA + 32 + d0) = p1;
    ushort4 p2, p3;
    p2.x = f2bf(otB0[4 * rg + 0] * invB); p2.y = f2bf(otB0[4 * rg + 1] * invB);
    p2.z = f2bf(otB0[4 * rg + 2] * invB); p2.w = f2bf(otB0[4 * rg + 3] * invB);
    *(ushort4*)(orowB + d0) = p2;
    p3.x = f2bf(otB1[4 * rg + 0] * invB); p3.y = f2bf(otB1[4 * rg + 1] * invB);
    p3.z = f2bf(otB1[4 * rg + 2] * invB); p3.w = f2bf(otB1[4 * rg + 3] * invB);
    *(ushort4*)(orowB + 32 + d0) = p3;
  }
}

// ---------------------------------------------------------------------------
// Output projection: fp32 result straight from accumulators.
// ---------------------------------------------------------------------------
__global__ __launch_bounds__(256) void out_proj_bf16(
    const unsigned short* __restrict__ aout,
    const unsigned short* __restrict__ wb,
    float* __restrict__ Cout) {
  const int nBase = blockIdx.x * 128;
  const int mBase = blockIdx.y * 128;

  __shared__ unsigned short As[128 * 32];
  __shared__ unsigned short Bs[128 * 32];

  floatx4 acc[4][4] = {};
  gemm_core(aout, wb + ((size_t)3 << 20), mBase, nBase, As, Bs, acc);

  const int t = threadIdx.x;
  const int lane = t & 63, w = t >> 6;
  const int wr = w >> 1, wc = w & 1;
  const int quad = lane >> 4, l15 = lane & 15;

#pragma unroll
  for (int mi = 0; mi < 4; ++mi)
#pragma unroll
    for (int ni = 0; ni < 4; ++ni) {
      const int n = nBase + wc * 64 + ni * 16 + l15;
#pragma unroll
      for (int r = 0; r < 4; ++r) {
        const int m = mBase + wr * 64 + mi * 16 + quad * 4 + r;
        Cout[(size_t)m * EMBED + n] = acc[mi][ni][r];
      }
    }
}

extern "C" void kernel_launch(void* const* d_in, const int* in_sizes, int n_in,
                              void* d_out, int out_size, void* d_ws, size_t ws_size,
                              hipStream_t stream) {
  const float* x  = (const float*)d_in[0];
  const float* wq = (const float*)d_in[1];
  const float* wk = (const float*)d_in[2];
  const float* wv = (const float*)d_in[3];
  const float* wo = (const float*)d_in[4];
  float* out = (float*)d_out;

  char* ws = (char*)d_ws;
  unsigned short* xb   = (unsigned short*)(ws);                  // 16.8 MB
  unsigned short* wb   = (unsigned short*)(ws + (16u << 20));    // 8.4 MB
  unsigned short* qkv  = (unsigned short*)(ws + (26u << 20));    // 50.3 MB
  unsigned short* aout = (unsigned short*)(ws + (76u << 20));    // 16.8 MB

  cast_bf16_kernel<<<12288, 256, 0, stream>>>(x, wq, wk, wv, wo, xb, wb);
  proj_qkv_bf16<<<dim3(EMBED / 128, MROWS / 128, 3), 256, 0, stream>>>(xb, wb, qkv);
  attn_mfma<<<256, 512, 0, stream>>>(qkv, aout);
  out_proj_bf16<<<dim3(EMBED / 128, MROWS / 128), 256, 0, stream>>>(aout, wb, out);
}

// Round 4
// 279.103 us; speedup vs baseline: 1.0953x; 1.0262x over previous
//
#include <hip/hip_runtime.h>
#include <math.h>

#define EMBED 1024
#define NHEAD 16
#define HDIM  64
#define BATCH 4
#define SEQ   2048
#define MROWS (BATCH * SEQ)   // 8192

typedef __attribute__((ext_vector_type(4))) short short4v;
typedef __attribute__((ext_vector_type(8))) short short8;
typedef __attribute__((ext_vector_type(4))) float floatx4;
typedef __attribute__((ext_vector_type(16))) float floatx16;
typedef __attribute__((ext_vector_type(2))) unsigned uint2v;

#if __has_builtin(__builtin_amdgcn_exp2f)
#define EXP2(x) __builtin_amdgcn_exp2f(x)
#else
#define EXP2(x) exp2f(x)
#endif

// RNE float -> bf16 (finite inputs only).
__device__ __forceinline__ unsigned short f2bf(float f) {
  unsigned u = __float_as_uint(f);
  u += 0x7fffu + ((u >> 16) & 1u);
  return (unsigned short)(u >> 16);
}

// Pack two floats as a bf16 pair. gfx950 has v_cvt_pk_bf16_f32 (1 VALU op).
#if __has_builtin(__builtin_amdgcn_cvt_pk_bf16_f32)
__device__ __forceinline__ unsigned pack2bf(float lo, float hi) {
  typedef __attribute__((ext_vector_type(2))) __bf16 bf2;
  union { bf2 b; unsigned u; } c;
  c.b = __builtin_amdgcn_cvt_pk_bf16_f32(lo, hi);
  return c.u;
}
#else
__device__ __forceinline__ unsigned pack2bf(float lo, float hi) {
  return ((__float_as_uint(lo) + 0x8000u) >> 16) |
         ((__float_as_uint(hi) + 0x8000u) & 0xffff0000u);
}
#endif

// v_permlane32_swap_b32: out0 = {a[0:31], b[0:31]-shifted-up},
// out1 = {a[32:63]-shifted-down, b[32:63]}.
__device__ __forceinline__ uint2v pl32swap(unsigned a, unsigned b) {
#if __has_builtin(__builtin_amdgcn_permlane32_swap)
  return __builtin_amdgcn_permlane32_swap(a, b, false, false);
#else
  uint2v r;
  unsigned ax = (unsigned)__shfl_xor((int)a, 32);
  unsigned bx = (unsigned)__shfl_xor((int)b, 32);
  const int hi = (int)((threadIdx.x & 63) >> 5);
  r[0] = hi ? bx : a;
  r[1] = hi ? b : ax;
  return r;
#endif
}

// Async global->LDS, 16 B per lane. lds dest MUST be wave-uniform base;
// HW adds lane*16.
__device__ __forceinline__ void gl_lds16(const void* g, void* l) {
  __builtin_amdgcn_global_load_lds(
      (const __attribute__((address_space(1))) unsigned int*)g,
      (__attribute__((address_space(3))) unsigned int*)l, 16, 0, 0);
}

// ---------------------------------------------------------------------------
// Cast fp32 -> bf16: x (8M elems) + 4 weights (1M each, contiguous dst).
// ---------------------------------------------------------------------------
__global__ __launch_bounds__(256) void cast_bf16_kernel(
    const float* __restrict__ x,  const float* __restrict__ wq,
    const float* __restrict__ wk, const float* __restrict__ wv,
    const float* __restrict__ wo,
    unsigned short* __restrict__ xb, unsigned short* __restrict__ wb) {
  const size_t NX = (size_t)MROWS * EMBED;                 // 2^23
  size_t i4 = ((size_t)blockIdx.x * 256 + threadIdx.x) * 4;
  const float* src;
  unsigned short* dst;
  size_t off;
  if (i4 < NX) {
    src = x; dst = xb; off = i4;
  } else {
    size_t j = i4 - NX;
    int r = (int)(j >> 20);
    off = j & ((1u << 20) - 1);
    src = (r == 0) ? wq : (r == 1) ? wk : (r == 2) ? wv : wo;
    dst = wb + ((size_t)r << 20);
  }
  float4 v = *(const float4*)(src + off);
  ushort4 o;
  o.x = f2bf(v.x); o.y = f2bf(v.y); o.z = f2bf(v.z); o.w = f2bf(v.w);
  *(ushort4*)(dst + off) = o;
}

// ---------------------------------------------------------------------------
// Shared 128x128xK bf16 GEMM core (m97 structure): Y = A @ B^T fragments.
// ---------------------------------------------------------------------------
__device__ __forceinline__ void gemm_core(
    const unsigned short* __restrict__ Amat,
    const unsigned short* __restrict__ Bmat,
    int mBase, int nBase,
    unsigned short* As, unsigned short* Bs,
    floatx4 acc[4][4]) {
  const int t = threadIdx.x;
  const int lane = t & 63, w = t >> 6;
  const int wr = w >> 1, wc = w & 1;
  const int quad = lane >> 4, l15 = lane & 15;

  const int f0 = (w * 2 + 0) * 64 + lane;
  const int f1 = (w * 2 + 1) * 64 + lane;
  const unsigned short* ga0 = Amat + (size_t)(mBase + (f0 >> 2)) * EMBED + (f0 & 3) * 8;
  const unsigned short* ga1 = Amat + (size_t)(mBase + (f1 >> 2)) * EMBED + (f1 & 3) * 8;
  const unsigned short* gb0 = Bmat + (size_t)(nBase + (f0 >> 2)) * EMBED + (f0 & 3) * 8;
  const unsigned short* gb1 = Bmat + (size_t)(nBase + (f1 >> 2)) * EMBED + (f1 & 3) * 8;
  unsigned short* la0 = As + (w * 2 + 0) * 512;
  unsigned short* la1 = As + (w * 2 + 1) * 512;
  unsigned short* lb0 = Bs + (w * 2 + 0) * 512;
  unsigned short* lb1 = Bs + (w * 2 + 1) * 512;

  for (int kb = 0; kb < EMBED; kb += 32) {
    __syncthreads();
    gl_lds16(ga0 + kb, la0);
    gl_lds16(ga1 + kb, la1);
    gl_lds16(gb0 + kb, lb0);
    gl_lds16(gb1 + kb, lb1);
    __syncthreads();
    short8 a[4], b[4];
#pragma unroll
    for (int mi = 0; mi < 4; ++mi)
      a[mi] = *(const short8*)&As[(wr * 64 + mi * 16 + l15) * 32 + quad * 8];
#pragma unroll
    for (int ni = 0; ni < 4; ++ni)
      b[ni] = *(const short8*)&Bs[(wc * 64 + ni * 16 + l15) * 32 + quad * 8];
#pragma unroll
    for (int mi = 0; mi < 4; ++mi)
#pragma unroll
      for (int ni = 0; ni < 4; ++ni)
        acc[mi][ni] = __builtin_amdgcn_mfma_f32_16x16x32_bf16(
            a[mi], b[ni], acc[mi][ni], 0, 0, 0);
  }
}

// ---------------------------------------------------------------------------
// QKV projection. Q is pre-scaled by C=(1/8)*log2(e) so attention's exp2
// argument is the raw QK^T score. Q,K: bf16 [b,h,s,d]; V: [b,h,d,s].
// ---------------------------------------------------------------------------
__global__ __launch_bounds__(256) void proj_qkv_bf16(
    const unsigned short* __restrict__ xb,
    const unsigned short* __restrict__ wb,
    unsigned short* __restrict__ qkv) {
  const int which = blockIdx.z;
  const unsigned short* W = wb + ((size_t)which << 20);
  const int nBase = blockIdx.x * 128;
  const int mBase = blockIdx.y * 128;

  __shared__ unsigned short As[128 * 32];
  __shared__ unsigned short Bs[128 * 32];

  floatx4 acc[4][4] = {};
  gemm_core(xb, W, mBase, nBase, As, Bs, acc);

  const int t = threadIdx.x;
  const int lane = t & 63, w = t >> 6;
  const int wr = w >> 1, wc = w & 1;
  const int quad = lane >> 4, l15 = lane & 15;

  unsigned short* out = qkv + (size_t)which * MROWS * EMBED;
  if (which < 2) {
    const float scale = (which == 0) ? 0.18033688f : 1.0f;  // (1/8)*log2(e)
#pragma unroll
    for (int mi = 0; mi < 4; ++mi)
#pragma unroll
      for (int ni = 0; ni < 4; ++ni) {
        const int n = nBase + wc * 64 + ni * 16 + l15;
        const int h = n >> 6, d = n & 63;
#pragma unroll
        for (int r = 0; r < 4; ++r) {
          const int m = mBase + wr * 64 + mi * 16 + quad * 4 + r;
          const int b = m >> 11, s = m & (SEQ - 1);
          out[(((size_t)(b * NHEAD + h) * SEQ) + s) * HDIM + d] =
              f2bf(acc[mi][ni][r] * scale);
        }
      }
  } else {
    // V^T: [b,h,d,s] — 4 consecutive s per lane -> packed 8 B store.
#pragma unroll
    for (int mi = 0; mi < 4; ++mi) {
      const int m0 = mBase + wr * 64 + mi * 16 + quad * 4;
      const int b = m0 >> 11, s0 = m0 & (SEQ - 1);
#pragma unroll
      for (int ni = 0; ni < 4; ++ni) {
        const int n = nBase + wc * 64 + ni * 16 + l15;
        const int h = n >> 6, d = n & 63;
        ushort4 pk;
        pk.x = f2bf(acc[mi][ni][0]); pk.y = f2bf(acc[mi][ni][1]);
        pk.z = f2bf(acc[mi][ni][2]); pk.w = f2bf(acc[mi][ni][3]);
        *(ushort4*)&out[((size_t)(b * NHEAD + h) * HDIM + d) * SEQ + s0] = pk;
      }
    }
  }
}

// ---------------------------------------------------------------------------
// MFMA flash attention, transposed-score formulation.
// R11: (a) PV now uses 32x32x16 MFMA (full matrix rate; the 32x32x8_1k op
// costs the same ~8cyc for half the FLOPs). B-frag k-layout (k=h2*8+j)
// needs the other lane-half's keys: built with v_permlane32_swap_b32 —
// swap(pk[i],pk[i+2]) gives B regs {0,2}, swap(pk[i+1],pk[i+3]) gives
// {1,3} (keys (r&3)+8*(r>>2)+4*h2 mapping). A-operand = one b128 per
// 8 keys. (b) 4-wave/256-thread blocks, 2 independent blocks per CU
// (grid 512, 2x64KB LDS): R10 showed MfmaUtil+VALUBusy ~= 88% —
// barrier-locked waves serialize the two pipes; independent block
// barriers let one block's exp2/VALU overlap the other's MFMA (m114).
// Counted vmcnt(8) (8 gl_lds per thread per tile), setprio kept.
// ---------------------------------------------------------------------------
__global__ __launch_bounds__(256, 2) void attn_mfma(
    const unsigned short* __restrict__ qkv,
    unsigned short* __restrict__ aout) {
  const unsigned short* Q = qkv;
  const unsigned short* K = qkv + (size_t)MROWS * EMBED;
  const unsigned short* V = qkv + 2 * (size_t)MROWS * EMBED;

  // XCD-locality decode: all 8 q-blocks of one bh land on one XCD.
  const int id = blockIdx.x;
  const int xcd = id & 7, slot = id >> 3;      // slot 0..63
  const int bh = xcd * 8 + (slot >> 3);
  const int qBase = (slot & 7) * 256;

  __shared__ unsigned short Ks[2 * 128 * 64];  // [buf][key][d], XOR-8 swizzled
  __shared__ unsigned short Vs[2 * 64 * 128];  // [buf][d][key], XOR-16 swizzled

  const int t = threadIdx.x;
  const int lane = t & 63, w = t >> 6;         // w 0..3
  const int h2 = lane >> 5;     // lane half (k-group selector in A/B frags)
  const int q31 = lane & 31;    // query within group / col within MFMA tile

  // Q B-frags (pre-scaled by (1/8)*log2e): B[k=d][n=q]. Two query groups.
  const unsigned short* qrowA =
      Q + ((size_t)bh * SEQ + qBase + w * 64 + q31) * HDIM;
  const unsigned short* qrowB = qrowA + 32 * HDIM;
  short8 qaA[4], qaB[4];
#pragma unroll
  for (int ds = 0; ds < 4; ++ds) {
    qaA[ds] = *(const short8*)(qrowA + ds * 16 + h2 * 8);
    qaB[ds] = *(const short8*)(qrowB + ds * 16 + h2 * 8);
  }

  // Staging: 256 threads stage 16 KB K + 16 KB V per tile -> 4 K-chunks +
  // 4 V-chunks of 16 B per thread (8 gl_lds per tile). Chunk index
  // c = i*256 + w*64 + lane occupies LDS bytes [c*16, c*16+16); the LDS
  // pointer passed to gl_lds16 is the wave-uniform part (HW adds lane*16),
  // the global pointer carries the per-lane swizzled address.
  const unsigned short* kbase = K + (size_t)bh * SEQ * HDIM;
  const unsigned short* vbase = V + (size_t)bh * HDIM * SEQ;
  const unsigned short* gk[4];
  const unsigned short* gv[4];
  unsigned short* lk[4];
  unsigned short* lv[4];
#pragma unroll
  for (int i = 0; i < 4; ++i) {
    const int c = i * 256 + t;                 // per-lane chunk 0..1023
    const int krow = c >> 3, kgrp = (c & 7) ^ (krow & 7);
    gk[i] = kbase + (size_t)krow * HDIM + kgrp * 8;
    const int vd = c >> 4, vj = (c & 15) ^ (vd & 15);
    gv[i] = vbase + (size_t)vd * SEQ + vj * 8;
    const int cu = i * 256 + w * 64;           // wave-uniform chunk base
    lk[i] = Ks + cu * 8;
    lv[i] = Vs + cu * 8;
  }

  floatx16 otA0 = {}, otA1 = {};  // group A O^T accum: d 0-31, 32-63
  floatx16 otB0 = {}, otB1 = {};  // group B
  float laccA = 0.0f, laccB = 0.0f;

  // Prologue: stage tile 0 into buffer 0.
#pragma unroll
  for (int i = 0; i < 4; ++i) {
    gl_lds16(gk[i], lk[i]);
    gl_lds16(gv[i], lv[i]);
  }

  for (int kt = 0; kt < SEQ; kt += 128) {
    const int cb = (kt >> 7) & 1;              // current buffer
    const int nb = cb ^ 1;                     // prefetch buffer
    const int nxt = (kt + 128) & (SEQ - 1);    // last iter re-stages tile 0
                                               // (keeps vmcnt count uniform)
    const int sOff = nb * 8192;                // ushort offset of prefetch buf
#pragma unroll
    for (int i = 0; i < 4; ++i) {
      gl_lds16(gk[i] + (size_t)nxt * HDIM, lk[i] + sOff);
      gl_lds16(gv[i] + nxt, lv[i] + sOff);
    }
    __builtin_amdgcn_sched_barrier(0);
    // Wait only for the PREVIOUS tile's 8 loads; this tile's 8 stay in
    // flight across the barrier (T4: never drain vmcnt to 0 in the loop).
    asm volatile("s_waitcnt vmcnt(8)" ::: "memory");
    __builtin_amdgcn_s_barrier();

    const int kOff = cb * 8192;                // ushort offsets, current buf
    const int vOff = cb * 8192;

#pragma unroll
    for (int sub = 0; sub < 2; ++sub) {
      const int koff = sub * 64;

      // S^T = K·Q^T: A[m=key][k=d] from Ks (swizzled b128), B = qa regs.
      // Each ka read feeds BOTH query groups (2 MFMAs per read).
      floatx16 stA0 = {}, stA1 = {}, stB0 = {}, stB1 = {};
      __builtin_amdgcn_s_setprio(1);
#pragma unroll
      for (int ds = 0; ds < 4; ++ds) {
        const int g = ds * 2 + h2;
        const int k0 = koff + q31;
        short8 ka0 = *(const short8*)&Ks[kOff + k0 * 64 + ((g ^ (q31 & 7)) * 8)];
        stA0 = __builtin_amdgcn_mfma_f32_32x32x16_bf16(ka0, qaA[ds], stA0, 0, 0, 0);
        stB0 = __builtin_amdgcn_mfma_f32_32x32x16_bf16(ka0, qaB[ds], stB0, 0, 0, 0);
        const int k1 = koff + 32 + q31;
        short8 ka1 = *(const short8*)&Ks[kOff + k1 * 64 + ((g ^ (q31 & 7)) * 8)];
        stA1 = __builtin_amdgcn_mfma_f32_32x32x16_bf16(ka1, qaA[ds], stA1, 0, 0, 0);
        stB1 = __builtin_amdgcn_mfma_f32_32x32x16_bf16(ka1, qaB[ds], stB1, 0, 0, 0);
      }
      __builtin_amdgcn_s_setprio(0);

      // P^T = exp2(S^T), fused exp+pack (short live ranges). All of a
      // lane's regs belong to its own query (col=q31) -> plain fp32 sum.
      unsigned pkA0[8], pkA1[8], pkB0[8], pkB1[8];
#pragma unroll
      for (int i = 0; i < 8; ++i) {
        float a0 = EXP2(stA0[2 * i]), b0 = EXP2(stA0[2 * i + 1]);
        float a1 = EXP2(stA1[2 * i]), b1 = EXP2(stA1[2 * i + 1]);
        laccA += (a0 + b0) + (a1 + b1);
        pkA0[i] = pack2bf(a0, b0);
        pkA1[i] = pack2bf(a1, b1);
        float c0 = EXP2(stB0[2 * i]), d0 = EXP2(stB0[2 * i + 1]);
        float c1 = EXP2(stB1[2 * i]), d1 = EXP2(stB1[2 * i + 1]);
        laccB += (c0 + d0) + (c1 + d1);
        pkB0[i] = pack2bf(c0, d0);
        pkB1[i] = pack2bf(c1, d1);
      }

      // PV: O^T += V^T·P^T, 4 k-steps of 16 keys (32x32x16 MFMA, full
      // rate). B-frag: lane needs keys ks+h2*8..+7 of its query; own regs
      // hold keys (r&3)+8*(r>>2)+4*h2 -> permlane32_swap(pk[i],pk[i+2])
      // yields B regs {0,2}, swap(pk[i+1],pk[i+3]) yields {1,3}.
      __builtin_amdgcn_s_setprio(1);
#pragma unroll
      for (int sp = 0; sp < 4; ++sp) {
        const unsigned* pA = (sp < 2) ? pkA0 : pkA1;
        const unsigned* pB = (sp < 2) ? pkB0 : pkB1;
        const int off = (sp & 1) * 4;
        uint2v ra0 = pl32swap(pA[off + 0], pA[off + 2]);
        uint2v ra1 = pl32swap(pA[off + 1], pA[off + 3]);
        uint2v rb0 = pl32swap(pB[off + 0], pB[off + 2]);
        uint2v rb1 = pl32swap(pB[off + 1], pB[off + 3]);
        union { unsigned u[4]; short8 v; } pbA, pbB;
        pbA.u[0] = ra0[0]; pbA.u[1] = ra1[0]; pbA.u[2] = ra0[1]; pbA.u[3] = ra1[1];
        pbB.u[0] = rb0[0]; pbB.u[1] = rb1[0]; pbB.u[2] = rb0[1]; pbB.u[3] = rb1[1];

        const int g8 = sub * 8 + sp * 2 + h2;  // global 8-key group
        const int pos = (g8 ^ (q31 & 15)) * 8;
        short8 va0 = *(const short8*)&Vs[vOff + q31 * 128 + pos];
        otA0 = __builtin_amdgcn_mfma_f32_32x32x16_bf16(va0, pbA.v, otA0, 0, 0, 0);
        otB0 = __builtin_amdgcn_mfma_f32_32x32x16_bf16(va0, pbB.v, otB0, 0, 0, 0);
        short8 va1 = *(const short8*)&Vs[vOff + (32 + q31) * 128 + pos];
        otA1 = __builtin_amdgcn_mfma_f32_32x32x16_bf16(va1, pbA.v, otA1, 0, 0, 0);
        otB1 = __builtin_amdgcn_mfma_f32_32x32x16_bf16(va1, pbB.v, otB1, 0, 0, 0);
      }
      __builtin_amdgcn_s_setprio(0);
    }

    __builtin_amdgcn_sched_barrier(0);
    __builtin_amdgcn_s_barrier();   // all waves done reading buf[cb]; next
                                    // iter's prefetch may overwrite it
  }
  asm volatile("s_waitcnt vmcnt(0)" ::: "memory");  // drain stray prefetch

  // Combine the two lane-halves' partial sums for each query group.
  const float totA = laccA + __shfl_xor(laccA, 32);
  const float totB = laccB + __shfl_xor(laccB, 32);
  const float invA = 1.0f / totA;
  const float invB = 1.0f / totB;

  // O^T C-layout: col=q (lane), row=d=(reg&3)+8*(reg>>2)+4*h2 (+32 for *1).
  const int b = bh >> 4, hh = bh & 15;
  unsigned short* orowA =
      aout + ((size_t)b * SEQ + qBase + w * 64 + q31) * EMBED + hh * HDIM;
  unsigned short* orowB = orowA + (size_t)32 * EMBED;
#pragma unroll
  for (int rg = 0; rg < 4; ++rg) {
    const int d0 = rg * 8 + h2 * 4;
    ushort4 p0, p1;
    p0.x = f2bf(otA0[4 * rg + 0] * invA); p0.y = f2bf(otA0[4 * rg + 1] * invA);
    p0.z = f2bf(otA0[4 * rg + 2] * invA); p0.w = f2bf(otA0[4 * rg + 3] * invA);
    *(ushort4*)(orowA + d0) = p0;
    p1.x = f2bf(otA1[4 * rg + 0] * invA); p1.y = f2bf(otA1[4 * rg + 1] * invA);
    p1.z = f2bf(otA1[4 * rg + 2] * invA); p1.w = f2bf(otA1[4 * rg + 3] * invA);
    *(ushort4*)(orowA + 32 + d0) = p1;
    ushort4 p2, p3;
    p2.x = f2bf(otB0[4 * rg + 0] * invB); p2.y = f2bf(otB0[4 * rg + 1] * invB);
    p2.z = f2bf(otB0[4 * rg + 2] * invB); p2.w = f2bf(otB0[4 * rg + 3] * invB);
    *(ushort4*)(orowB + d0) = p2;
    p3.x = f2bf(otB1[4 * rg + 0] * invB); p3.y = f2bf(otB1[4 * rg + 1] * invB);
    p3.z = f2bf(otB1[4 * rg + 2] * invB); p3.w = f2bf(otB1[4 * rg + 3] * invB);
    *(ushort4*)(orowB + 32 + d0) = p3;
  }
}

// ---------------------------------------------------------------------------
// Output projection: fp32 result straight from accumulators.
// ---------------------------------------------------------------------------
__global__ __launch_bounds__(256) void out_proj_bf16(
    const unsigned short* __restrict__ aout,
    const unsigned short* __restrict__ wb,
    float* __restrict__ Cout) {
  const int nBase = blockIdx.x * 128;
  const int mBase = blockIdx.y * 128;

  __shared__ unsigned short As[128 * 32];
  __shared__ unsigned short Bs[128 * 32];

  floatx4 acc[4][4] = {};
  gemm_core(aout, wb + ((size_t)3 << 20), mBase, nBase, As, Bs, acc);

  const int t = threadIdx.x;
  const int lane = t & 63, w = t >> 6;
  const int wr = w >> 1, wc = w & 1;
  const int quad = lane >> 4, l15 = lane & 15;

#pragma unroll
  for (int mi = 0; mi < 4; ++mi)
#pragma unroll
    for (int ni = 0; ni < 4; ++ni) {
      const int n = nBase + wc * 64 + ni * 16 + l15;
#pragma unroll
      for (int r = 0; r < 4; ++r) {
        const int m = mBase + wr * 64 + mi * 16 + quad * 4 + r;
        Cout[(size_t)m * EMBED + n] = acc[mi][ni][r];
      }
    }
}

extern "C" void kernel_launch(void* const* d_in, const int* in_sizes, int n_in,
                              void* d_out, int out_size, void* d_ws, size_t ws_size,
                              hipStream_t stream) {
  const float* x  = (const float*)d_in[0];
  const float* wq = (const float*)d_in[1];
  const float* wk = (const float*)d_in[2];
  const float* wv = (const float*)d_in[3];
  const float* wo = (const float*)d_in[4];
  float* out = (float*)d_out;

  char* ws = (char*)d_ws;
  unsigned short* xb   = (unsigned short*)(ws);                  // 16.8 MB
  unsigned short* wb   = (unsigned short*)(ws + (16u << 20));    // 8.4 MB
  unsigned short* qkv  = (unsigned short*)(ws + (26u << 20));    // 50.3 MB
  unsigned short* aout = (unsigned short*)(ws + (76u << 20));    // 16.8 MB

  cast_bf16_kernel<<<12288, 256, 0, stream>>>(x, wq, wk, wv, wo, xb, wb);
  proj_qkv_bf16<<<dim3(EMBED / 128, MROWS / 128, 3), 256, 0, stream>>>(xb, wb, qkv);
  attn_mfma<<<512, 256, 0, stream>>>(qkv, aout);
  out_proj_bf16<<<dim3(EMBED / 128, MROWS / 128), 256, 0, stream>>>(aout, wb, out);
}

// Round 5
// 270.513 us; speedup vs baseline: 1.1301x; 1.0318x over previous
//
#include <hip/hip_runtime.h>
#include <math.h>

#define EMBED 1024
#define NHEAD 16
#define HDIM  64
#define BATCH 4
#define SEQ   2048
#define MROWS (BATCH * SEQ)   // 8192

typedef __attribute__((ext_vector_type(4))) short short4v;
typedef __attribute__((ext_vector_type(8))) short short8;
typedef __attribute__((ext_vector_type(4))) float floatx4;
typedef __attribute__((ext_vector_type(16))) float floatx16;
typedef __attribute__((ext_vector_type(2))) unsigned uint2v;

#if __has_builtin(__builtin_amdgcn_exp2f)
#define EXP2(x) __builtin_amdgcn_exp2f(x)
#else
#define EXP2(x) exp2f(x)
#endif

// RNE float -> bf16 (finite inputs only).
__device__ __forceinline__ unsigned short f2bf(float f) {
  unsigned u = __float_as_uint(f);
  u += 0x7fffu + ((u >> 16) & 1u);
  return (unsigned short)(u >> 16);
}

// Pack two floats as a bf16 pair. gfx950 has v_cvt_pk_bf16_f32 (1 VALU op).
#if __has_builtin(__builtin_amdgcn_cvt_pk_bf16_f32)
__device__ __forceinline__ unsigned pack2bf(float lo, float hi) {
  typedef __attribute__((ext_vector_type(2))) __bf16 bf2;
  union { bf2 b; unsigned u; } c;
  c.b = __builtin_amdgcn_cvt_pk_bf16_f32(lo, hi);
  return c.u;
}
#else
__device__ __forceinline__ unsigned pack2bf(float lo, float hi) {
  return ((__float_as_uint(lo) + 0x8000u) >> 16) |
         ((__float_as_uint(hi) + 0x8000u) & 0xffff0000u);
}
#endif

// v_permlane32_swap_b32: out0 = {a[0:31], b[0:31]-shifted-up},
// out1 = {a[32:63]-shifted-down, b[32:63]}.
__device__ __forceinline__ uint2v pl32swap(unsigned a, unsigned b) {
#if __has_builtin(__builtin_amdgcn_permlane32_swap)
  return __builtin_amdgcn_permlane32_swap(a, b, false, false);
#else
  uint2v r;
  unsigned ax = (unsigned)__shfl_xor((int)a, 32);
  unsigned bx = (unsigned)__shfl_xor((int)b, 32);
  const int hi = (int)((threadIdx.x & 63) >> 5);
  r[0] = hi ? bx : a;
  r[1] = hi ? b : ax;
  return r;
#endif
}

// Async global->LDS, 16 B per lane. lds dest MUST be wave-uniform base;
// HW adds lane*16.
__device__ __forceinline__ void gl_lds16(const void* g, void* l) {
  __builtin_amdgcn_global_load_lds(
      (const __attribute__((address_space(1))) unsigned int*)g,
      (__attribute__((address_space(3))) unsigned int*)l, 16, 0, 0);
}

// ---------------------------------------------------------------------------
// Cast fp32 -> bf16: x (8M elems) + 4 weights (1M each, contiguous dst).
// ---------------------------------------------------------------------------
__global__ __launch_bounds__(256) void cast_bf16_kernel(
    const float* __restrict__ x,  const float* __restrict__ wq,
    const float* __restrict__ wk, const float* __restrict__ wv,
    const float* __restrict__ wo,
    unsigned short* __restrict__ xb, unsigned short* __restrict__ wb) {
  const size_t NX = (size_t)MROWS * EMBED;                 // 2^23
  size_t i4 = ((size_t)blockIdx.x * 256 + threadIdx.x) * 4;
  const float* src;
  unsigned short* dst;
  size_t off;
  if (i4 < NX) {
    src = x; dst = xb; off = i4;
  } else {
    size_t j = i4 - NX;
    int r = (int)(j >> 20);
    off = j & ((1u << 20) - 1);
    src = (r == 0) ? wq : (r == 1) ? wk : (r == 2) ? wv : wo;
    dst = wb + ((size_t)r << 20);
  }
  float4 v = *(const float4*)(src + off);
  ushort4 o;
  o.x = f2bf(v.x); o.y = f2bf(v.y); o.z = f2bf(v.z); o.w = f2bf(v.w);
  *(ushort4*)(dst + off) = o;
}

// ---------------------------------------------------------------------------
// Shared 128x128xK bf16 GEMM core (m97 structure): Y = A @ B^T fragments.
// ---------------------------------------------------------------------------
__device__ __forceinline__ void gemm_core(
    const unsigned short* __restrict__ Amat,
    const unsigned short* __restrict__ Bmat,
    int mBase, int nBase,
    unsigned short* As, unsigned short* Bs,
    floatx4 acc[4][4]) {
  const int t = threadIdx.x;
  const int lane = t & 63, w = t >> 6;
  const int wr = w >> 1, wc = w & 1;
  const int quad = lane >> 4, l15 = lane & 15;

  const int f0 = (w * 2 + 0) * 64 + lane;
  const int f1 = (w * 2 + 1) * 64 + lane;
  const unsigned short* ga0 = Amat + (size_t)(mBase + (f0 >> 2)) * EMBED + (f0 & 3) * 8;
  const unsigned short* ga1 = Amat + (size_t)(mBase + (f1 >> 2)) * EMBED + (f1 & 3) * 8;
  const unsigned short* gb0 = Bmat + (size_t)(nBase + (f0 >> 2)) * EMBED + (f0 & 3) * 8;
  const unsigned short* gb1 = Bmat + (size_t)(nBase + (f1 >> 2)) * EMBED + (f1 & 3) * 8;
  unsigned short* la0 = As + (w * 2 + 0) * 512;
  unsigned short* la1 = As + (w * 2 + 1) * 512;
  unsigned short* lb0 = Bs + (w * 2 + 0) * 512;
  unsigned short* lb1 = Bs + (w * 2 + 1) * 512;

  for (int kb = 0; kb < EMBED; kb += 32) {
    __syncthreads();
    gl_lds16(ga0 + kb, la0);
    gl_lds16(ga1 + kb, la1);
    gl_lds16(gb0 + kb, lb0);
    gl_lds16(gb1 + kb, lb1);
    __syncthreads();
    short8 a[4], b[4];
#pragma unroll
    for (int mi = 0; mi < 4; ++mi)
      a[mi] = *(const short8*)&As[(wr * 64 + mi * 16 + l15) * 32 + quad * 8];
#pragma unroll
    for (int ni = 0; ni < 4; ++ni)
      b[ni] = *(const short8*)&Bs[(wc * 64 + ni * 16 + l15) * 32 + quad * 8];
#pragma unroll
    for (int mi = 0; mi < 4; ++mi)
#pragma unroll
      for (int ni = 0; ni < 4; ++ni)
        acc[mi][ni] = __builtin_amdgcn_mfma_f32_16x16x32_bf16(
            a[mi], b[ni], acc[mi][ni], 0, 0, 0);
  }
}

// ---------------------------------------------------------------------------
// QKV projection. Q is pre-scaled by C=(1/8)*log2(e) so attention's exp2
// argument is the raw QK^T score. Q,K: bf16 [b,h,s,d]; V: [b,h,d,s].
// R12: 1-D grid + bijective XCD-aware decode. Old dim3(8,64,3) mapping put
// XCD = linear%8 = nBase -> each XCD streamed the ENTIRE 16.8MB A 3x
// (FETCH 200MB, HBM-read-bound at 2.25 TB/s = the whole 89us). Now each
// XCD owns a contiguous 8-mBase chunk (A chunk 2MB, L2-resident) swept
// over all nBase and which: per-XCD working set A 2MB + B 2MB = 4MB L2.
// ---------------------------------------------------------------------------
__global__ __launch_bounds__(256) void proj_qkv_bf16(
    const unsigned short* __restrict__ xb,
    const unsigned short* __restrict__ wb,
    unsigned short* __restrict__ qkv) {
  const int id = blockIdx.x;                 // 0..1535
  const int xcd = id & 7;
  const int r = id >> 3;                     // 0..191
  const int which = r >> 6;                  // 0..2
  const int rm = r & 63;                     // 0..63
  const int mBase = (xcd * 8 + (rm >> 3)) * 128;
  const int nBase = (rm & 7) * 128;

  const unsigned short* W = wb + ((size_t)which << 20);

  __shared__ unsigned short As[128 * 32];
  __shared__ unsigned short Bs[128 * 32];

  floatx4 acc[4][4] = {};
  gemm_core(xb, W, mBase, nBase, As, Bs, acc);

  const int t = threadIdx.x;
  const int lane = t & 63, w = t >> 6;
  const int wr = w >> 1, wc = w & 1;
  const int quad = lane >> 4, l15 = lane & 15;

  unsigned short* out = qkv + (size_t)which * MROWS * EMBED;
  if (which < 2) {
    const float scale = (which == 0) ? 0.18033688f : 1.0f;  // (1/8)*log2(e)
#pragma unroll
    for (int mi = 0; mi < 4; ++mi)
#pragma unroll
      for (int ni = 0; ni < 4; ++ni) {
        const int n = nBase + wc * 64 + ni * 16 + l15;
        const int h = n >> 6, d = n & 63;
#pragma unroll
        for (int r2 = 0; r2 < 4; ++r2) {
          const int m = mBase + wr * 64 + mi * 16 + quad * 4 + r2;
          const int b = m >> 11, s = m & (SEQ - 1);
          out[(((size_t)(b * NHEAD + h) * SEQ) + s) * HDIM + d] =
              f2bf(acc[mi][ni][r2] * scale);
        }
      }
  } else {
    // V^T: [b,h,d,s] — 4 consecutive s per lane -> packed 8 B store.
#pragma unroll
    for (int mi = 0; mi < 4; ++mi) {
      const int m0 = mBase + wr * 64 + mi * 16 + quad * 4;
      const int b = m0 >> 11, s0 = m0 & (SEQ - 1);
#pragma unroll
      for (int ni = 0; ni < 4; ++ni) {
        const int n = nBase + wc * 64 + ni * 16 + l15;
        const int h = n >> 6, d = n & 63;
        ushort4 pk;
        pk.x = f2bf(acc[mi][ni][0]); pk.y = f2bf(acc[mi][ni][1]);
        pk.z = f2bf(acc[mi][ni][2]); pk.w = f2bf(acc[mi][ni][3]);
        *(ushort4*)&out[((size_t)(b * NHEAD + h) * HDIM + d) * SEQ + s0] = pk;
      }
    }
  }
}

// ---------------------------------------------------------------------------
// MFMA flash attention, transposed-score formulation (R11 structure).
// ---------------------------------------------------------------------------
__global__ __launch_bounds__(256, 2) void attn_mfma(
    const unsigned short* __restrict__ qkv,
    unsigned short* __restrict__ aout) {
  const unsigned short* Q = qkv;
  const unsigned short* K = qkv + (size_t)MROWS * EMBED;
  const unsigned short* V = qkv + 2 * (size_t)MROWS * EMBED;

  // XCD-locality decode: all 8 q-blocks of one bh land on one XCD.
  const int id = blockIdx.x;
  const int xcd = id & 7, slot = id >> 3;      // slot 0..63
  const int bh = xcd * 8 + (slot >> 3);
  const int qBase = (slot & 7) * 256;

  __shared__ unsigned short Ks[2 * 128 * 64];  // [buf][key][d], XOR-8 swizzled
  __shared__ unsigned short Vs[2 * 64 * 128];  // [buf][d][key], XOR-16 swizzled

  const int t = threadIdx.x;
  const int lane = t & 63, w = t >> 6;         // w 0..3
  const int h2 = lane >> 5;     // lane half (k-group selector in A/B frags)
  const int q31 = lane & 31;    // query within group / col within MFMA tile

  // Q B-frags (pre-scaled by (1/8)*log2e): B[k=d][n=q]. Two query groups.
  const unsigned short* qrowA =
      Q + ((size_t)bh * SEQ + qBase + w * 64 + q31) * HDIM;
  const unsigned short* qrowB = qrowA + 32 * HDIM;
  short8 qaA[4], qaB[4];
#pragma unroll
  for (int ds = 0; ds < 4; ++ds) {
    qaA[ds] = *(const short8*)(qrowA + ds * 16 + h2 * 8);
    qaB[ds] = *(const short8*)(qrowB + ds * 16 + h2 * 8);
  }

  // Staging: 256 threads stage 16 KB K + 16 KB V per tile -> 4 K-chunks +
  // 4 V-chunks of 16 B per thread (8 gl_lds per tile).
  const unsigned short* kbase = K + (size_t)bh * SEQ * HDIM;
  const unsigned short* vbase = V + (size_t)bh * HDIM * SEQ;
  const unsigned short* gk[4];
  const unsigned short* gv[4];
  unsigned short* lk[4];
  unsigned short* lv[4];
#pragma unroll
  for (int i = 0; i < 4; ++i) {
    const int c = i * 256 + t;                 // per-lane chunk 0..1023
    const int krow = c >> 3, kgrp = (c & 7) ^ (krow & 7);
    gk[i] = kbase + (size_t)krow * HDIM + kgrp * 8;
    const int vd = c >> 4, vj = (c & 15) ^ (vd & 15);
    gv[i] = vbase + (size_t)vd * SEQ + vj * 8;
    const int cu = i * 256 + w * 64;           // wave-uniform chunk base
    lk[i] = Ks + cu * 8;
    lv[i] = Vs + cu * 8;
  }

  floatx16 otA0 = {}, otA1 = {};  // group A O^T accum: d 0-31, 32-63
  floatx16 otB0 = {}, otB1 = {};  // group B
  float laccA = 0.0f, laccB = 0.0f;

  // Prologue: stage tile 0 into buffer 0.
#pragma unroll
  for (int i = 0; i < 4; ++i) {
    gl_lds16(gk[i], lk[i]);
    gl_lds16(gv[i], lv[i]);
  }

  for (int kt = 0; kt < SEQ; kt += 128) {
    const int cb = (kt >> 7) & 1;              // current buffer
    const int nb = cb ^ 1;                     // prefetch buffer
    const int nxt = (kt + 128) & (SEQ - 1);    // last iter re-stages tile 0
                                               // (keeps vmcnt count uniform)
    const int sOff = nb * 8192;                // ushort offset of prefetch buf
#pragma unroll
    for (int i = 0; i < 4; ++i) {
      gl_lds16(gk[i] + (size_t)nxt * HDIM, lk[i] + sOff);
      gl_lds16(gv[i] + nxt, lv[i] + sOff);
    }
    __builtin_amdgcn_sched_barrier(0);
    // Wait only for the PREVIOUS tile's 8 loads; this tile's 8 stay in
    // flight across the barrier (T4: never drain vmcnt to 0 in the loop).
    asm volatile("s_waitcnt vmcnt(8)" ::: "memory");
    __builtin_amdgcn_s_barrier();

    const int kOff = cb * 8192;                // ushort offsets, current buf
    const int vOff = cb * 8192;

#pragma unroll
    for (int sub = 0; sub < 2; ++sub) {
      const int koff = sub * 64;

      // S^T = K·Q^T: A[m=key][k=d] from Ks (swizzled b128), B = qa regs.
      // Each ka read feeds BOTH query groups (2 MFMAs per read).
      floatx16 stA0 = {}, stA1 = {}, stB0 = {}, stB1 = {};
      __builtin_amdgcn_s_setprio(1);
#pragma unroll
      for (int ds = 0; ds < 4; ++ds) {
        const int g = ds * 2 + h2;
        const int k0 = koff + q31;
        short8 ka0 = *(const short8*)&Ks[kOff + k0 * 64 + ((g ^ (q31 & 7)) * 8)];
        stA0 = __builtin_amdgcn_mfma_f32_32x32x16_bf16(ka0, qaA[ds], stA0, 0, 0, 0);
        stB0 = __builtin_amdgcn_mfma_f32_32x32x16_bf16(ka0, qaB[ds], stB0, 0, 0, 0);
        const int k1 = koff + 32 + q31;
        short8 ka1 = *(const short8*)&Ks[kOff + k1 * 64 + ((g ^ (q31 & 7)) * 8)];
        stA1 = __builtin_amdgcn_mfma_f32_32x32x16_bf16(ka1, qaA[ds], stA1, 0, 0, 0);
        stB1 = __builtin_amdgcn_mfma_f32_32x32x16_bf16(ka1, qaB[ds], stB1, 0, 0, 0);
      }
      __builtin_amdgcn_s_setprio(0);

      // P^T = exp2(S^T), fused exp+pack (short live ranges). All of a
      // lane's regs belong to its own query (col=q31) -> plain fp32 sum.
      unsigned pkA0[8], pkA1[8], pkB0[8], pkB1[8];
#pragma unroll
      for (int i = 0; i < 8; ++i) {
        float a0 = EXP2(stA0[2 * i]), b0 = EXP2(stA0[2 * i + 1]);
        float a1 = EXP2(stA1[2 * i]), b1 = EXP2(stA1[2 * i + 1]);
        laccA += (a0 + b0) + (a1 + b1);
        pkA0[i] = pack2bf(a0, b0);
        pkA1[i] = pack2bf(a1, b1);
        float c0 = EXP2(stB0[2 * i]), d0 = EXP2(stB0[2 * i + 1]);
        float c1 = EXP2(stB1[2 * i]), d1 = EXP2(stB1[2 * i + 1]);
        laccB += (c0 + d0) + (c1 + d1);
        pkB0[i] = pack2bf(c0, d0);
        pkB1[i] = pack2bf(c1, d1);
      }

      // PV: O^T += V^T·P^T, 4 k-steps of 16 keys (32x32x16 MFMA, full
      // rate). B-frag: lane needs keys ks+h2*8..+7 of its query; own regs
      // hold keys (r&3)+8*(r>>2)+4*h2 -> permlane32_swap(pk[i],pk[i+2])
      // yields B regs {0,2}, swap(pk[i+1],pk[i+3]) yields {1,3}.
      __builtin_amdgcn_s_setprio(1);
#pragma unroll
      for (int sp = 0; sp < 4; ++sp) {
        const unsigned* pA = (sp < 2) ? pkA0 : pkA1;
        const unsigned* pB = (sp < 2) ? pkB0 : pkB1;
        const int off = (sp & 1) * 4;
        uint2v ra0 = pl32swap(pA[off + 0], pA[off + 2]);
        uint2v ra1 = pl32swap(pA[off + 1], pA[off + 3]);
        uint2v rb0 = pl32swap(pB[off + 0], pB[off + 2]);
        uint2v rb1 = pl32swap(pB[off + 1], pB[off + 3]);
        union { unsigned u[4]; short8 v; } pbA, pbB;
        pbA.u[0] = ra0[0]; pbA.u[1] = ra1[0]; pbA.u[2] = ra0[1]; pbA.u[3] = ra1[1];
        pbB.u[0] = rb0[0]; pbB.u[1] = rb1[0]; pbB.u[2] = rb0[1]; pbB.u[3] = rb1[1];

        const int g8 = sub * 8 + sp * 2 + h2;  // global 8-key group
        const int pos = (g8 ^ (q31 & 15)) * 8;
        short8 va0 = *(const short8*)&Vs[vOff + q31 * 128 + pos];
        otA0 = __builtin_amdgcn_mfma_f32_32x32x16_bf16(va0, pbA.v, otA0, 0, 0, 0);
        otB0 = __builtin_amdgcn_mfma_f32_32x32x16_bf16(va0, pbB.v, otB0, 0, 0, 0);
        short8 va1 = *(const short8*)&Vs[vOff + (32 + q31) * 128 + pos];
        otA1 = __builtin_amdgcn_mfma_f32_32x32x16_bf16(va1, pbA.v, otA1, 0, 0, 0);
        otB1 = __builtin_amdgcn_mfma_f32_32x32x16_bf16(va1, pbB.v, otB1, 0, 0, 0);
      }
      __builtin_amdgcn_s_setprio(0);
    }

    __builtin_amdgcn_sched_barrier(0);
    __builtin_amdgcn_s_barrier();   // all waves done reading buf[cb]; next
                                    // iter's prefetch may overwrite it
  }
  asm volatile("s_waitcnt vmcnt(0)" ::: "memory");  // drain stray prefetch

  // Combine the two lane-halves' partial sums for each query group.
  const float totA = laccA + __shfl_xor(laccA, 32);
  const float totB = laccB + __shfl_xor(laccB, 32);
  const float invA = 1.0f / totA;
  const float invB = 1.0f / totB;

  // O^T C-layout: col=q (lane), row=d=(reg&3)+8*(reg>>2)+4*h2 (+32 for *1).
  const int b = bh >> 4, hh = bh & 15;
  unsigned short* orowA =
      aout + ((size_t)b * SEQ + qBase + w * 64 + q31) * EMBED + hh * HDIM;
  unsigned short* orowB = orowA + (size_t)32 * EMBED;
#pragma unroll
  for (int rg = 0; rg < 4; ++rg) {
    const int d0 = rg * 8 + h2 * 4;
    ushort4 p0, p1;
    p0.x = f2bf(otA0[4 * rg + 0] * invA); p0.y = f2bf(otA0[4 * rg + 1] * invA);
    p0.z = f2bf(otA0[4 * rg + 2] * invA); p0.w = f2bf(otA0[4 * rg + 3] * invA);
    *(ushort4*)(orowA + d0) = p0;
    p1.x = f2bf(otA1[4 * rg + 0] * invA); p1.y = f2bf(otA1[4 * rg + 1] * invA);
    p1.z = f2bf(otA1[4 * rg + 2] * invA); p1.w = f2bf(otA1[4 * rg + 3] * invA);
    *(ushort4*)(orowA + 32 + d0) = p1;
    ushort4 p2, p3;
    p2.x = f2bf(otB0[4 * rg + 0] * invB); p2.y = f2bf(otB0[4 * rg + 1] * invB);
    p2.z = f2bf(otB0[4 * rg + 2] * invB); p2.w = f2bf(otB0[4 * rg + 3] * invB);
    *(ushort4*)(orowB + d0) = p2;
    p3.x = f2bf(otB1[4 * rg + 0] * invB); p3.y = f2bf(otB1[4 * rg + 1] * invB);
    p3.z = f2bf(otB1[4 * rg + 2] * invB); p3.w = f2bf(otB1[4 * rg + 3] * invB);
    *(ushort4*)(orowB + 32 + d0) = p3;
  }
}

// ---------------------------------------------------------------------------
// Output projection: fp32 result straight from accumulators.
// R12: 1-D grid + bijective XCD-aware decode (same rationale as proj).
// ---------------------------------------------------------------------------
__global__ __launch_bounds__(256) void out_proj_bf16(
    const unsigned short* __restrict__ aout,
    const unsigned short* __restrict__ wb,
    float* __restrict__ Cout) {
  const int id = blockIdx.x;                 // 0..511
  const int xcd = id & 7;
  const int r = id >> 3;                     // 0..63
  const int mBase = (xcd * 8 + (r >> 3)) * 128;
  const int nBase = (r & 7) * 128;

  __shared__ unsigned short As[128 * 32];
  __shared__ unsigned short Bs[128 * 32];

  floatx4 acc[4][4] = {};
  gemm_core(aout, wb + ((size_t)3 << 20), mBase, nBase, As, Bs, acc);

  const int t = threadIdx.x;
  const int lane = t & 63, w = t >> 6;
  const int wr = w >> 1, wc = w & 1;
  const int quad = lane >> 4, l15 = lane & 15;

#pragma unroll
  for (int mi = 0; mi < 4; ++mi)
#pragma unroll
    for (int ni = 0; ni < 4; ++ni) {
      const int n = nBase + wc * 64 + ni * 16 + l15;
#pragma unroll
      for (int r2 = 0; r2 < 4; ++r2) {
        const int m = mBase + wr * 64 + mi * 16 + quad * 4 + r2;
        Cout[(size_t)m * EMBED + n] = acc[mi][ni][r2];
      }
    }
}

extern "C" void kernel_launch(void* const* d_in, const int* in_sizes, int n_in,
                              void* d_out, int out_size, void* d_ws, size_t ws_size,
                              hipStream_t stream) {
  const float* x  = (const float*)d_in[0];
  const float* wq = (const float*)d_in[1];
  const float* wk = (const float*)d_in[2];
  const float* wv = (const float*)d_in[3];
  const float* wo = (const float*)d_in[4];
  float* out = (float*)d_out;

  char* ws = (char*)d_ws;
  unsigned short* xb   = (unsigned short*)(ws);                  // 16.8 MB
  unsigned short* wb   = (unsigned short*)(ws + (16u << 20));    // 8.4 MB
  unsigned short* qkv  = (unsigned short*)(ws + (26u << 20));    // 50.3 MB
  unsigned short* aout = (unsigned short*)(ws + (76u << 20));    // 16.8 MB

  cast_bf16_kernel<<<12288, 256, 0, stream>>>(x, wq, wk, wv, wo, xb, wb);
  proj_qkv_bf16<<<1536, 256, 0, stream>>>(xb, wb, qkv);
  attn_mfma<<<512, 256, 0, stream>>>(qkv, aout);
  out_proj_bf16<<<512, 256, 0, stream>>>(aout, wb, out);
}

// Round 6
// 269.959 us; speedup vs baseline: 1.1324x; 1.0021x over previous
//
#include <hip/hip_runtime.h>
#include <math.h>

#define EMBED 1024
#define NHEAD 16
#define HDIM  64
#define BATCH 4
#define SEQ   2048
#define MROWS (BATCH * SEQ)   // 8192

typedef __attribute__((ext_vector_type(4))) short short4v;
typedef __attribute__((ext_vector_type(8))) short short8;
typedef __attribute__((ext_vector_type(4))) float floatx4;
typedef __attribute__((ext_vector_type(16))) float floatx16;
typedef __attribute__((ext_vector_type(2))) unsigned uint2v;

#if __has_builtin(__builtin_amdgcn_exp2f)
#define EXP2(x) __builtin_amdgcn_exp2f(x)
#else
#define EXP2(x) exp2f(x)
#endif

// RNE float -> bf16 (finite inputs only).
__device__ __forceinline__ unsigned short f2bf(float f) {
  unsigned u = __float_as_uint(f);
  u += 0x7fffu + ((u >> 16) & 1u);
  return (unsigned short)(u >> 16);
}

// Pack two floats as a bf16 pair. gfx950 has v_cvt_pk_bf16_f32 (1 VALU op).
#if __has_builtin(__builtin_amdgcn_cvt_pk_bf16_f32)
__device__ __forceinline__ unsigned pack2bf(float lo, float hi) {
  typedef __attribute__((ext_vector_type(2))) __bf16 bf2;
  union { bf2 b; unsigned u; } c;
  c.b = __builtin_amdgcn_cvt_pk_bf16_f32(lo, hi);
  return c.u;
}
#else
__device__ __forceinline__ unsigned pack2bf(float lo, float hi) {
  return ((__float_as_uint(lo) + 0x8000u) >> 16) |
         ((__float_as_uint(hi) + 0x8000u) & 0xffff0000u);
}
#endif

// v_permlane32_swap_b32: out0 = {a[0:31], b[0:31]-shifted-up},
// out1 = {a[32:63]-shifted-down, b[32:63]}.
__device__ __forceinline__ uint2v pl32swap(unsigned a, unsigned b) {
#if __has_builtin(__builtin_amdgcn_permlane32_swap)
  return __builtin_amdgcn_permlane32_swap(a, b, false, false);
#else
  uint2v r;
  unsigned ax = (unsigned)__shfl_xor((int)a, 32);
  unsigned bx = (unsigned)__shfl_xor((int)b, 32);
  const int hi = (int)((threadIdx.x & 63) >> 5);
  r[0] = hi ? bx : a;
  r[1] = hi ? b : ax;
  return r;
#endif
}

// Async global->LDS, 16 B per lane. lds dest MUST be wave-uniform base;
// HW adds lane*16.
__device__ __forceinline__ void gl_lds16(const void* g, void* l) {
  __builtin_amdgcn_global_load_lds(
      (const __attribute__((address_space(1))) unsigned int*)g,
      (__attribute__((address_space(3))) unsigned int*)l, 16, 0, 0);
}

// ---------------------------------------------------------------------------
// Cast fp32 -> bf16: x (8M elems) + 4 weights (1M each, contiguous dst).
// ---------------------------------------------------------------------------
__global__ __launch_bounds__(256) void cast_bf16_kernel(
    const float* __restrict__ x,  const float* __restrict__ wq,
    const float* __restrict__ wk, const float* __restrict__ wv,
    const float* __restrict__ wo,
    unsigned short* __restrict__ xb, unsigned short* __restrict__ wb) {
  const size_t NX = (size_t)MROWS * EMBED;                 // 2^23
  size_t i4 = ((size_t)blockIdx.x * 256 + threadIdx.x) * 4;
  const float* src;
  unsigned short* dst;
  size_t off;
  if (i4 < NX) {
    src = x; dst = xb; off = i4;
  } else {
    size_t j = i4 - NX;
    int r = (int)(j >> 20);
    off = j & ((1u << 20) - 1);
    src = (r == 0) ? wq : (r == 1) ? wk : (r == 2) ? wv : wo;
    dst = wb + ((size_t)r << 20);
  }
  float4 v = *(const float4*)(src + off);
  ushort4 o;
  o.x = f2bf(v.x); o.y = f2bf(v.y); o.z = f2bf(v.z); o.w = f2bf(v.w);
  *(ushort4*)(dst + off) = o;
}

// ---------------------------------------------------------------------------
// Shared 128x128xK bf16 GEMM core (m97 structure): Y = A @ B^T fragments.
// ---------------------------------------------------------------------------
__device__ __forceinline__ void gemm_core(
    const unsigned short* __restrict__ Amat,
    const unsigned short* __restrict__ Bmat,
    int mBase, int nBase,
    unsigned short* As, unsigned short* Bs,
    floatx4 acc[4][4]) {
  const int t = threadIdx.x;
  const int lane = t & 63, w = t >> 6;
  const int wr = w >> 1, wc = w & 1;
  const int quad = lane >> 4, l15 = lane & 15;

  const int f0 = (w * 2 + 0) * 64 + lane;
  const int f1 = (w * 2 + 1) * 64 + lane;
  const unsigned short* ga0 = Amat + (size_t)(mBase + (f0 >> 2)) * EMBED + (f0 & 3) * 8;
  const unsigned short* ga1 = Amat + (size_t)(mBase + (f1 >> 2)) * EMBED + (f1 & 3) * 8;
  const unsigned short* gb0 = Bmat + (size_t)(nBase + (f0 >> 2)) * EMBED + (f0 & 3) * 8;
  const unsigned short* gb1 = Bmat + (size_t)(nBase + (f1 >> 2)) * EMBED + (f1 & 3) * 8;
  unsigned short* la0 = As + (w * 2 + 0) * 512;
  unsigned short* la1 = As + (w * 2 + 1) * 512;
  unsigned short* lb0 = Bs + (w * 2 + 0) * 512;
  unsigned short* lb1 = Bs + (w * 2 + 1) * 512;

  for (int kb = 0; kb < EMBED; kb += 32) {
    __syncthreads();
    gl_lds16(ga0 + kb, la0);
    gl_lds16(ga1 + kb, la1);
    gl_lds16(gb0 + kb, lb0);
    gl_lds16(gb1 + kb, lb1);
    __syncthreads();
    short8 a[4], b[4];
#pragma unroll
    for (int mi = 0; mi < 4; ++mi)
      a[mi] = *(const short8*)&As[(wr * 64 + mi * 16 + l15) * 32 + quad * 8];
#pragma unroll
    for (int ni = 0; ni < 4; ++ni)
      b[ni] = *(const short8*)&Bs[(wc * 64 + ni * 16 + l15) * 32 + quad * 8];
#pragma unroll
    for (int mi = 0; mi < 4; ++mi)
#pragma unroll
      for (int ni = 0; ni < 4; ++ni)
        acc[mi][ni] = __builtin_amdgcn_mfma_f32_16x16x32_bf16(
            a[mi], b[ni], acc[mi][ni], 0, 0, 0);
  }
}

// ---------------------------------------------------------------------------
// QKV projection. Q is pre-scaled by C=(1/8)*log2(e) so attention's exp2
// argument is the raw QK^T score. Q,K: bf16 [b,h,s,d]; V: [b,h,d,s].
// R12: 1-D grid + bijective XCD-aware decode (per-XCD A chunk L2-resident).
// ---------------------------------------------------------------------------
__global__ __launch_bounds__(256) void proj_qkv_bf16(
    const unsigned short* __restrict__ xb,
    const unsigned short* __restrict__ wb,
    unsigned short* __restrict__ qkv) {
  const int id = blockIdx.x;                 // 0..1535
  const int xcd = id & 7;
  const int r = id >> 3;                     // 0..191
  const int which = r >> 6;                  // 0..2
  const int rm = r & 63;                     // 0..63
  const int mBase = (xcd * 8 + (rm >> 3)) * 128;
  const int nBase = (rm & 7) * 128;

  const unsigned short* W = wb + ((size_t)which << 20);

  __shared__ unsigned short As[128 * 32];
  __shared__ unsigned short Bs[128 * 32];

  floatx4 acc[4][4] = {};
  gemm_core(xb, W, mBase, nBase, As, Bs, acc);

  const int t = threadIdx.x;
  const int lane = t & 63, w = t >> 6;
  const int wr = w >> 1, wc = w & 1;
  const int quad = lane >> 4, l15 = lane & 15;

  unsigned short* out = qkv + (size_t)which * MROWS * EMBED;
  if (which < 2) {
    const float scale = (which == 0) ? 0.18033688f : 1.0f;  // (1/8)*log2(e)
#pragma unroll
    for (int mi = 0; mi < 4; ++mi)
#pragma unroll
      for (int ni = 0; ni < 4; ++ni) {
        const int n = nBase + wc * 64 + ni * 16 + l15;
        const int h = n >> 6, d = n & 63;
#pragma unroll
        for (int r2 = 0; r2 < 4; ++r2) {
          const int m = mBase + wr * 64 + mi * 16 + quad * 4 + r2;
          const int b = m >> 11, s = m & (SEQ - 1);
          out[(((size_t)(b * NHEAD + h) * SEQ) + s) * HDIM + d] =
              f2bf(acc[mi][ni][r2] * scale);
        }
      }
  } else {
    // V^T: [b,h,d,s] — 4 consecutive s per lane -> packed 8 B store.
#pragma unroll
    for (int mi = 0; mi < 4; ++mi) {
      const int m0 = mBase + wr * 64 + mi * 16 + quad * 4;
      const int b = m0 >> 11, s0 = m0 & (SEQ - 1);
#pragma unroll
      for (int ni = 0; ni < 4; ++ni) {
        const int n = nBase + wc * 64 + ni * 16 + l15;
        const int h = n >> 6, d = n & 63;
        ushort4 pk;
        pk.x = f2bf(acc[mi][ni][0]); pk.y = f2bf(acc[mi][ni][1]);
        pk.z = f2bf(acc[mi][ni][2]); pk.w = f2bf(acc[mi][ni][3]);
        *(ushort4*)&out[((size_t)(b * NHEAD + h) * HDIM + d) * SEQ + s0] = pk;
      }
    }
  }
}

// ---------------------------------------------------------------------------
// MFMA flash attention, transposed-score formulation.
// R13: intra-wave pipe interleaving. R12 showed MfmaUtil(34)+VALUBusy(53)
// ~= 87% additive: strict phase walls (QK cluster -> 64 exp2 -> PV cluster)
// serialize matrix and VALU pipes. Now each 32-key half runs {8 QK MFMAs}
// then immediately {exp2+pack+permlane+4 PV MFMAs} per 16-key group, all
// straight-line: the scheduler hoists the next half's QK LDS-reads/MFMAs
// over the current half's exp2 chain, and PV MFMAs intersperse with VALU.
// Also halves live st regs (64->32), cutting AGPR<->VGPR shuffle traffic.
// setprio kept only around QK clusters.
// ---------------------------------------------------------------------------
__global__ __launch_bounds__(256, 2) void attn_mfma(
    const unsigned short* __restrict__ qkv,
    unsigned short* __restrict__ aout) {
  const unsigned short* Q = qkv;
  const unsigned short* K = qkv + (size_t)MROWS * EMBED;
  const unsigned short* V = qkv + 2 * (size_t)MROWS * EMBED;

  // XCD-locality decode: all 8 q-blocks of one bh land on one XCD.
  const int id = blockIdx.x;
  const int xcd = id & 7, slot = id >> 3;      // slot 0..63
  const int bh = xcd * 8 + (slot >> 3);
  const int qBase = (slot & 7) * 256;

  __shared__ unsigned short Ks[2 * 128 * 64];  // [buf][key][d], XOR-8 swizzled
  __shared__ unsigned short Vs[2 * 64 * 128];  // [buf][d][key], XOR-16 swizzled

  const int t = threadIdx.x;
  const int lane = t & 63, w = t >> 6;         // w 0..3
  const int h2 = lane >> 5;     // lane half (k-group selector in A/B frags)
  const int q31 = lane & 31;    // query within group / col within MFMA tile

  // Q B-frags (pre-scaled by (1/8)*log2e): B[k=d][n=q]. Two query groups.
  const unsigned short* qrowA =
      Q + ((size_t)bh * SEQ + qBase + w * 64 + q31) * HDIM;
  const unsigned short* qrowB = qrowA + 32 * HDIM;
  short8 qaA[4], qaB[4];
#pragma unroll
  for (int ds = 0; ds < 4; ++ds) {
    qaA[ds] = *(const short8*)(qrowA + ds * 16 + h2 * 8);
    qaB[ds] = *(const short8*)(qrowB + ds * 16 + h2 * 8);
  }

  // Staging: 256 threads stage 16 KB K + 16 KB V per tile -> 4 K-chunks +
  // 4 V-chunks of 16 B per thread (8 gl_lds per tile).
  const unsigned short* kbase = K + (size_t)bh * SEQ * HDIM;
  const unsigned short* vbase = V + (size_t)bh * HDIM * SEQ;
  const unsigned short* gk[4];
  const unsigned short* gv[4];
  unsigned short* lk[4];
  unsigned short* lv[4];
#pragma unroll
  for (int i = 0; i < 4; ++i) {
    const int c = i * 256 + t;                 // per-lane chunk 0..1023
    const int krow = c >> 3, kgrp = (c & 7) ^ (krow & 7);
    gk[i] = kbase + (size_t)krow * HDIM + kgrp * 8;
    const int vd = c >> 4, vj = (c & 15) ^ (vd & 15);
    gv[i] = vbase + (size_t)vd * SEQ + vj * 8;
    const int cu = i * 256 + w * 64;           // wave-uniform chunk base
    lk[i] = Ks + cu * 8;
    lv[i] = Vs + cu * 8;
  }

  floatx16 otA0 = {}, otA1 = {};  // group A O^T accum: d 0-31, 32-63
  floatx16 otB0 = {}, otB1 = {};  // group B
  float laccA = 0.0f, laccB = 0.0f;

  // Prologue: stage tile 0 into buffer 0.
#pragma unroll
  for (int i = 0; i < 4; ++i) {
    gl_lds16(gk[i], lk[i]);
    gl_lds16(gv[i], lv[i]);
  }

  for (int kt = 0; kt < SEQ; kt += 128) {
    const int cb = (kt >> 7) & 1;              // current buffer
    const int nb = cb ^ 1;                     // prefetch buffer
    const int nxt = (kt + 128) & (SEQ - 1);    // last iter re-stages tile 0
                                               // (keeps vmcnt count uniform)
    const int sOff = nb * 8192;                // ushort offset of prefetch buf
#pragma unroll
    for (int i = 0; i < 4; ++i) {
      gl_lds16(gk[i] + (size_t)nxt * HDIM, lk[i] + sOff);
      gl_lds16(gv[i] + nxt, lv[i] + sOff);
    }
    __builtin_amdgcn_sched_barrier(0);
    // Wait only for the PREVIOUS tile's 8 loads; this tile's 8 stay in
    // flight across the barrier (T4: never drain vmcnt to 0 in the loop).
    asm volatile("s_waitcnt vmcnt(8)" ::: "memory");
    __builtin_amdgcn_s_barrier();

    const int kOff = cb * 8192;                // ushort offsets, current buf
    const int vOff = cb * 8192;

#pragma unroll
    for (int sub = 0; sub < 2; ++sub) {
      const int koff = sub * 64;
#pragma unroll
      for (int kh = 0; kh < 2; ++kh) {
        // S^T = K·Q^T for one 32-key half: A[m=key][k=d] from Ks (swizzled
        // b128), B = qa regs. Each ka read feeds BOTH query groups.
        const int krow = koff + kh * 32 + q31;
        floatx16 stA = {}, stB = {};
        __builtin_amdgcn_s_setprio(1);
#pragma unroll
        for (int ds = 0; ds < 4; ++ds) {
          const int g = ds * 2 + h2;
          short8 ka = *(const short8*)&Ks[kOff + krow * 64 + ((g ^ (q31 & 7)) * 8)];
          stA = __builtin_amdgcn_mfma_f32_32x32x16_bf16(ka, qaA[ds], stA, 0, 0, 0);
          stB = __builtin_amdgcn_mfma_f32_32x32x16_bf16(ka, qaB[ds], stB, 0, 0, 0);
        }
        __builtin_amdgcn_s_setprio(0);

        // Per 16-key group: exp2 + pack + permlane + 4 PV MFMAs, fused so
        // VALU and matrix pipes interleave across groups/halves.
        // Lane's own st regs hold keys (r&3)+8*(r>>2)+4*h2; PV B-frag needs
        // keys ks+h2*8..+7 -> permlane32_swap(p[0],p[2]) gives B regs {0,2},
        // swap(p[1],p[3]) gives {1,3}.
#pragma unroll
        for (int spp = 0; spp < 2; ++spp) {
          unsigned pA[4], pB[4];
#pragma unroll
          for (int i = 0; i < 4; ++i) {
            float a0 = EXP2(stA[8 * spp + 2 * i]);
            float a1 = EXP2(stA[8 * spp + 2 * i + 1]);
            laccA += a0 + a1;
            pA[i] = pack2bf(a0, a1);
            float b0 = EXP2(stB[8 * spp + 2 * i]);
            float b1 = EXP2(stB[8 * spp + 2 * i + 1]);
            laccB += b0 + b1;
            pB[i] = pack2bf(b0, b1);
          }
          uint2v ra0 = pl32swap(pA[0], pA[2]);
          uint2v ra1 = pl32swap(pA[1], pA[3]);
          uint2v rb0 = pl32swap(pB[0], pB[2]);
          uint2v rb1 = pl32swap(pB[1], pB[3]);
          union { unsigned u[4]; short8 v; } pbA, pbB;
          pbA.u[0] = ra0[0]; pbA.u[1] = ra1[0]; pbA.u[2] = ra0[1]; pbA.u[3] = ra1[1];
          pbB.u[0] = rb0[0]; pbB.u[1] = rb1[0]; pbB.u[2] = rb0[1]; pbB.u[3] = rb1[1];

          const int g8 = sub * 8 + (kh * 2 + spp) * 2 + h2;  // 8-key group
          const int pos = (g8 ^ (q31 & 15)) * 8;
          short8 va0 = *(const short8*)&Vs[vOff + q31 * 128 + pos];
          short8 va1 = *(const short8*)&Vs[vOff + (32 + q31) * 128 + pos];
          otA0 = __builtin_amdgcn_mfma_f32_32x32x16_bf16(va0, pbA.v, otA0, 0, 0, 0);
          otB0 = __builtin_amdgcn_mfma_f32_32x32x16_bf16(va0, pbB.v, otB0, 0, 0, 0);
          otA1 = __builtin_amdgcn_mfma_f32_32x32x16_bf16(va1, pbA.v, otA1, 0, 0, 0);
          otB1 = __builtin_amdgcn_mfma_f32_32x32x16_bf16(va1, pbB.v, otB1, 0, 0, 0);
        }
      }
    }

    __builtin_amdgcn_sched_barrier(0);
    __builtin_amdgcn_s_barrier();   // all waves done reading buf[cb]; next
                                    // iter's prefetch may overwrite it
  }
  asm volatile("s_waitcnt vmcnt(0)" ::: "memory");  // drain stray prefetch

  // Combine the two lane-halves' partial sums for each query group.
  const float totA = laccA + __shfl_xor(laccA, 32);
  const float totB = laccB + __shfl_xor(laccB, 32);
  const float invA = 1.0f / totA;
  const float invB = 1.0f / totB;

  // O^T C-layout: col=q (lane), row=d=(reg&3)+8*(reg>>2)+4*h2 (+32 for *1).
  const int b = bh >> 4, hh = bh & 15;
  unsigned short* orowA =
      aout + ((size_t)b * SEQ + qBase + w * 64 + q31) * EMBED + hh * HDIM;
  unsigned short* orowB = orowA + (size_t)32 * EMBED;
#pragma unroll
  for (int rg = 0; rg < 4; ++rg) {
    const int d0 = rg * 8 + h2 * 4;
    ushort4 p0, p1;
    p0.x = f2bf(otA0[4 * rg + 0] * invA); p0.y = f2bf(otA0[4 * rg + 1] * invA);
    p0.z = f2bf(otA0[4 * rg + 2] * invA); p0.w = f2bf(otA0[4 * rg + 3] * invA);
    *(ushort4*)(orowA + d0) = p0;
    p1.x = f2bf(otA1[4 * rg + 0] * invA); p1.y = f2bf(otA1[4 * rg + 1] * invA);
    p1.z = f2bf(otA1[4 * rg + 2] * invA); p1.w = f2bf(otA1[4 * rg + 3] * invA);
    *(ushort4*)(orowA + 32 + d0) = p1;
    ushort4 p2, p3;
    p2.x = f2bf(otB0[4 * rg + 0] * invB); p2.y = f2bf(otB0[4 * rg + 1] * invB);
    p2.z = f2bf(otB0[4 * rg + 2] * invB); p2.w = f2bf(otB0[4 * rg + 3] * invB);
    *(ushort4*)(orowB + d0) = p2;
    p3.x = f2bf(otB1[4 * rg + 0] * invB); p3.y = f2bf(otB1[4 * rg + 1] * invB);
    p3.z = f2bf(otB1[4 * rg + 2] * invB); p3.w = f2bf(otB1[4 * rg + 3] * invB);
    *(ushort4*)(orowB + 32 + d0) = p3;
  }
}

// ---------------------------------------------------------------------------
// Output projection: fp32 result straight from accumulators.
// R12: 1-D grid + bijective XCD-aware decode (same rationale as proj).
// ---------------------------------------------------------------------------
__global__ __launch_bounds__(256) void out_proj_bf16(
    const unsigned short* __restrict__ aout,
    const unsigned short* __restrict__ wb,
    float* __restrict__ Cout) {
  const int id = blockIdx.x;                 // 0..511
  const int xcd = id & 7;
  const int r = id >> 3;                     // 0..63
  const int mBase = (xcd * 8 + (r >> 3)) * 128;
  const int nBase = (r & 7) * 128;

  __shared__ unsigned short As[128 * 32];
  __shared__ unsigned short Bs[128 * 32];

  floatx4 acc[4][4] = {};
  gemm_core(aout, wb + ((size_t)3 << 20), mBase, nBase, As, Bs, acc);

  const int t = threadIdx.x;
  const int lane = t & 63, w = t >> 6;
  const int wr = w >> 1, wc = w & 1;
  const int quad = lane >> 4, l15 = lane & 15;

#pragma unroll
  for (int mi = 0; mi < 4; ++mi)
#pragma unroll
    for (int ni = 0; ni < 4; ++ni) {
      const int n = nBase + wc * 64 + ni * 16 + l15;
#pragma unroll
      for (int r2 = 0; r2 < 4; ++r2) {
        const int m = mBase + wr * 64 + mi * 16 + quad * 4 + r2;
        Cout[(size_t)m * EMBED + n] = acc[mi][ni][r2];
      }
    }
}

extern "C" void kernel_launch(void* const* d_in, const int* in_sizes, int n_in,
                              void* d_out, int out_size, void* d_ws, size_t ws_size,
                              hipStream_t stream) {
  const float* x  = (const float*)d_in[0];
  const float* wq = (const float*)d_in[1];
  const float* wk = (const float*)d_in[2];
  const float* wv = (const float*)d_in[3];
  const float* wo = (const float*)d_in[4];
  float* out = (float*)d_out;

  char* ws = (char*)d_ws;
  unsigned short* xb   = (unsigned short*)(ws);                  // 16.8 MB
  unsigned short* wb   = (unsigned short*)(ws + (16u << 20));    // 8.4 MB
  unsigned short* qkv  = (unsigned short*)(ws + (26u << 20));    // 50.3 MB
  unsigned short* aout = (unsigned short*)(ws + (76u << 20));    // 16.8 MB

  cast_bf16_kernel<<<12288, 256, 0, stream>>>(x, wq, wk, wv, wo, xb, wb);
  proj_qkv_bf16<<<1536, 256, 0, stream>>>(xb, wb, qkv);
  attn_mfma<<<512, 256, 0, stream>>>(qkv, aout);
  out_proj_bf16<<<512, 256, 0, stream>>>(aout, wb, out);
}